// Round 7
// baseline (377.983 us; speedup 1.0000x reference)
//
#include <hip/hip_runtime.h>

// MOTCAT_Surv R17. R16 passed (absmax 0.0156, 362 us); screen2 still top (66.5 us)
// but now LATENCY-bound: grid (4,64) = 1 block/CU = 1 wave/SIMD (Occ 10.4%), so
// LDS chains + barrier drains are fully exposed (2500 cyc/tile vs ~1100 of work).
// This round: restore 8 waves/CU keeping R16's per-row LDS amortization -- block
// covers 64 rows, wave w = rowset (w>>1, 32 rows x 2 bfr sets) x col-HALF (w&1,
// 16 of 32 tile cols); grid (4,128) = 512 blocks = 2 blocks/CU. Per wave/tile:
// 8 ds_read_b128, 16 MFMA, 8 med3 inserts. Col-halves merged once at the end via
// 4KB LDS (g-butterfly -> 8 sorted keys/row/half -> 64-thread 8-key insert).
// Stream-top-6 superset argument holds at every merge stage. Everything outside
// screen2 byte-identical to R16 (proven).

typedef __attribute__((ext_vector_type(8))) short short8;
typedef __attribute__((ext_vector_type(4))) short short4v;
typedef __attribute__((ext_vector_type(4))) float f32x4;

__device__ inline float bf2f(unsigned short b) {
    unsigned u = ((unsigned)b) << 16;
    return __builtin_bit_cast(float, u);
}
__device__ inline unsigned short f2bf(float f) {   // round-to-nearest-even
    unsigned u = __builtin_bit_cast(unsigned, f);
    unsigned r = u + 0x7fffu + ((u >> 16) & 1u);
    return (unsigned short)(r >> 16);
}
__device__ inline f32x4 mfma16(short8 a, short8 b, f32x4 c) {
    return __builtin_amdgcn_mfma_f32_16x16x32_bf16(a, b, c, 0, 0, 0);
}
// A-frag: lane holds A[m=lane&15][k=(lane>>4)*8+j]; B-frag: B[k][n=lane&15];
// C/D: col=lane&15 (n), row=(lane>>4)*4+reg (m) (learn_hip m89).

__device__ inline void gload_lds16(const unsigned short* g, unsigned short* l) {
    __builtin_amdgcn_global_load_lds(
        (const __attribute__((address_space(1))) void*)g,
        (__attribute__((address_space(3))) void*)l, 16, 0, 0);
}

// split fp32 -> bf16 hi/mid/lo (residual subtractions are exact: operands close)
__device__ inline void split8(const f32x4 v0, const f32x4 v1,
                              short8& hi, short8& md, short8& lo) {
    #pragma unroll
    for (int e = 0; e < 8; e++) {
        float a = (e < 4) ? v0[e] : v1[e - 4];
        unsigned short h = f2bf(a);
        float r1 = a - bf2f(h);
        unsigned short m = f2bf(r1);
        float r2 = r1 - bf2f(m);
        unsigned short l = f2bf(r2);
        hi[e] = (short)h; md[e] = (short)m; lo[e] = (short)l;
    }
}

// ---------------------------------------------------------------------------
// tsplit3: W [K][N] fp32 -> Bt planes [n][k] bf16 (hi, mid, lo) at out + p*PS.
// ---------------------------------------------------------------------------
__launch_bounds__(256)
__global__ void tsplit3(const float* __restrict__ W, unsigned short* __restrict__ out,
                        int K, int N, int PS) {
    __shared__ float T[32][33];
    const int t = threadIdx.x;
    const int n0 = blockIdx.x * 32, k0 = blockIdx.y * 32;
    {
        const int r = t >> 3, c = (t & 7) * 4;
        f32x4 v = *(const f32x4*)&W[(size_t)(k0 + r) * N + n0 + c];
        #pragma unroll
        for (int e = 0; e < 4; e++) T[r][c + e] = v[e];
    }
    __syncthreads();
    const int nr = t >> 3, kc = (t & 7) * 4;
    short4v h4, m4, l4;
    #pragma unroll
    for (int e = 0; e < 4; e++) {
        float a = T[kc + e][nr];
        unsigned short h = f2bf(a);
        float r1 = a - bf2f(h);
        unsigned short m = f2bf(r1);
        float r2 = r1 - bf2f(m);
        h4[e] = (short)h; m4[e] = (short)m; l4[e] = (short)f2bf(r2);
    }
    const size_t o = (size_t)(n0 + nr) * K + k0 + kc;
    *(short4v*)&out[o] = h4;
    *(short4v*)&out[(size_t)PS + o] = m4;
    *(short4v*)&out[(size_t)2 * PS + o] = l4;
}

// ---------------------------------------------------------------------------
// gemmM (proven R15): C = act(A@B + bias) (+=C if ACCUM) on matrix cores.
// ---------------------------------------------------------------------------
template <int ASPLIT, int ACT, int ACCUM>
__launch_bounds__(256)
__global__ void gemmM(const void* __restrict__ Av,
                      const unsigned short* __restrict__ Bt,
                      const float* __restrict__ bias, float* __restrict__ C,
                      int N, int K, int BPS) {
    constexpr int APL = ASPLIT ? 3 : 1;
    constexpr int BPL = ASPLIT ? 3 : 2;
    __shared__ __align__(16) unsigned short LA[2][APL * 2048];
    __shared__ __align__(16) unsigned short LB[2][BPL * 2048];
    const int t = threadIdx.x;
    const int r0 = blockIdx.y * 64, c0 = blockIdx.x * 64;
    const int lid = t & 63, w = t >> 6, g = lid >> 4, m16 = lid & 15;
    const int wm = w >> 1, wn = w & 1;

    f32x4 acc[2][2];
    #pragma unroll
    for (int mf = 0; mf < 2; mf++)
        #pragma unroll
        for (int nf = 0; nf < 2; nf++) acc[mf][nf] = {0.0f, 0.0f, 0.0f, 0.0f};

    const int KT = K >> 5;
    const size_t aoff = (size_t)(r0 + (t >> 2)) * K + (t & 3) * 8;
    const size_t boff = (size_t)(c0 + (t >> 2)) * K + (t & 3) * 8;

    {
        #pragma unroll
        for (int p = 0; p < BPL; p++)
            gload_lds16(&Bt[(size_t)p * BPS + boff], &LB[0][p * 2048 + 8 * t]);
        if (ASPLIT) {
            const float* A = (const float*)Av;
            f32x4 v0 = *(const f32x4*)&A[aoff];
            f32x4 v1 = *(const f32x4*)&A[aoff + 4];
            short8 hi, md, lo;
            split8(v0, v1, hi, md, lo);
            *(short8*)&LA[0][8 * t] = hi;
            *(short8*)&LA[0][2048 + 8 * t] = md;
            *(short8*)&LA[0][4096 + 8 * t] = lo;
        } else {
            const unsigned short* A16 = (const unsigned short*)Av;
            gload_lds16(&A16[aoff], &LA[0][8 * t]);
        }
    }
    __syncthreads();

    for (int kt = 0; kt < KT; kt++) {
        const int cur = kt & 1, nxt = cur ^ 1;
        const bool hn = (kt + 1) < KT;
        f32x4 v0, v1;
        if (hn) {
            const size_t ko = (size_t)(kt + 1) * 32;
            #pragma unroll
            for (int p = 0; p < BPL; p++)
                gload_lds16(&Bt[(size_t)p * BPS + boff + ko],
                            &LB[nxt][p * 2048 + 8 * t]);
            if (ASPLIT) {
                const float* A = (const float*)Av;
                v0 = *(const f32x4*)&A[aoff + ko];
                v1 = *(const f32x4*)&A[aoff + ko + 4];
            } else {
                const unsigned short* A16 = (const unsigned short*)Av;
                gload_lds16(&A16[aoff + ko], &LA[nxt][8 * t]);
            }
        }
        short8 af[2][APL], bf[2][BPL];
        #pragma unroll
        for (int mf = 0; mf < 2; mf++) {
            const int row = wm * 32 + mf * 16 + m16;
            #pragma unroll
            for (int p = 0; p < APL; p++)
                af[mf][p] = *(const short8*)&LA[cur][p * 2048 + row * 32 + g * 8];
        }
        #pragma unroll
        for (int nf = 0; nf < 2; nf++) {
            const int col = wn * 32 + nf * 16 + m16;
            #pragma unroll
            for (int p = 0; p < BPL; p++)
                bf[nf][p] = *(const short8*)&LB[cur][p * 2048 + col * 32 + g * 8];
        }
        #pragma unroll
        for (int mf = 0; mf < 2; mf++)
            #pragma unroll
            for (int nf = 0; nf < 2; nf++) {
                if (ASPLIT) {
                    acc[mf][nf] = mfma16(af[mf][0], bf[nf][0], acc[mf][nf]); // hh
                    acc[mf][nf] = mfma16(af[mf][0], bf[nf][1], acc[mf][nf]); // hm
                    acc[mf][nf] = mfma16(af[mf][1], bf[nf][0], acc[mf][nf]); // mh
                    acc[mf][nf] = mfma16(af[mf][0], bf[nf][2], acc[mf][nf]); // hl
                    acc[mf][nf] = mfma16(af[mf][1], bf[nf][1], acc[mf][nf]); // mm
                    acc[mf][nf] = mfma16(af[mf][2], bf[nf][0], acc[mf][nf]); // lh
                } else {
                    acc[mf][nf] = mfma16(af[mf][0], bf[nf][0], acc[mf][nf]);
                    acc[mf][nf] = mfma16(af[mf][0], bf[nf][1], acc[mf][nf]);
                }
            }
        if (hn && ASPLIT) {
            short8 hi, md, lo;
            split8(v0, v1, hi, md, lo);
            *(short8*)&LA[nxt][8 * t] = hi;
            *(short8*)&LA[nxt][2048 + 8 * t] = md;
            *(short8*)&LA[nxt][4096 + 8 * t] = lo;
        }
        __syncthreads();
    }

    #pragma unroll
    for (int nf = 0; nf < 2; nf++) {
        const int col = c0 + wn * 32 + nf * 16 + m16;
        const float bv = bias[col];
        #pragma unroll
        for (int mf = 0; mf < 2; mf++) {
            #pragma unroll
            for (int r = 0; r < 4; r++) {
                const int row = r0 + wm * 32 + mf * 16 + g * 4 + r;
                float v = acc[mf][nf][r] + bv;
                if (ACT == 1) v = v > 0.0f ? v : 0.01f * v;
                size_t idx = (size_t)row * N + col;
                if (ACCUM) v += C[idx];
                C[idx] = v;
            }
        }
    }
}

// ---------------------------------------------------------------------------
__global__ void colsum_k(const float* __restrict__ x, float* __restrict__ out) {
    int d = threadIdx.x, b = blockIdx.x;
    float s = 0.0f;
    int i0 = b * 128;
    for (int i = 0; i < 128; i++) s += x[(size_t)(i0 + i) * 256 + d];
    out[b * 256 + d] = s;
}
__global__ void meanred_k(const float* __restrict__ p, float* __restrict__ mean) {
    int d = threadIdx.x;
    float s = 0.0f;
    for (int b = 0; b < 64; b++) s += p[b * 256 + d];
    mean[d] = s * (1.0f / 8192.0f);
}
__global__ void finalize_x(float* __restrict__ x, const float* __restrict__ mean) {
    size_t idx = (size_t)blockIdx.x * blockDim.x + threadIdx.x;
    f32x4 v = *(f32x4*)&x[idx * 4];
    int d4 = (int)((idx * 4) & 255);
    f32x4 m = *(const f32x4*)&mean[d4];
    #pragma unroll
    for (int e = 0; e < 4; e++) v[e] = (v[e] + m[e]) * 0.5f;
    *(f32x4*)&x[idx * 4] = v;
}
__global__ void f2bf_k(const float* __restrict__ src, unsigned short* __restrict__ dst, int n4) {
    size_t idx = (size_t)blockIdx.x * blockDim.x + threadIdx.x;
    if (idx >= (size_t)n4) return;
    f32x4 v = *(const f32x4*)&src[idx * 4];
    short4v h;
    #pragma unroll
    for (int e = 0; e < 4; e++) h[e] = (short)f2bf(v[e]);
    *(short4v*)&dst[idx * 4] = h;
}
// rowsum[i] = sum_d et[i][d]
__launch_bounds__(256)
__global__ void rowsum_k(const float* __restrict__ et, float* __restrict__ rowsum) {
    const int w = threadIdx.x >> 6, l = threadIdx.x & 63;
    const int i = blockIdx.x * 4 + w;
    f32x4 v = *(const f32x4*)&et[(size_t)i * 256 + l * 4];
    float s = v[0] + v[1] + v[2] + v[3];
    #pragma unroll
    for (int st = 1; st < 64; st <<= 1) s += __shfl_xor(s, st);
    if (l == 0) rowsum[i] = s;
}

// ---------------------------------------------------------------------------
// float keys (col in low-11 mantissa bits), med3 insert. Ascending, tk[0]=min.
// ---------------------------------------------------------------------------
__device__ inline float packkey(float v, unsigned col) {
    unsigned u = (__builtin_bit_cast(unsigned, v) & 0xFFFFF800u) | col;
    return __builtin_bit_cast(float, u);
}
template<int NK>
__device__ inline void insf(float (&tk)[NK], float key) {
    #pragma unroll
    for (int k = 0; k < NK - 1; k++)
        tk[k] = __builtin_amdgcn_fmed3f(key, tk[k + 1], tk[k]);
    tk[NK - 1] = fmaxf(tk[NK - 1], key);
}

// ---------------------------------------------------------------------------
// screen2 R17: block = 64 rows, 4 waves; wave w = rowset (w>>1: 32 rows, 2 bfr
// sets) x col-half (w&1: 16 of 32 tile cols). Grid (4,128) = 2 blocks/CU =
// 8 waves/CU (2/SIMD -> latency hidden). Per wave/tile: 8 swizzled ds_read_b128,
// 16 MFMA, 8 med3 inserts. Lane (g,m16) of wave (rs,ch): rows r0+rs*32+{0,16}+m16,
// cols tile*32 + ch*16 + g*4 + r. End: g-butterfly top-8/half -> mbuf ->
// 64-thread cross-half merge -> candi top-8/quarter/row.
// ---------------------------------------------------------------------------
__launch_bounds__(256)
__global__ void screen2(const unsigned short* __restrict__ eh16,
                        const unsigned short* __restrict__ et16,
                        int* __restrict__ candi) {
    __shared__ __align__(16) unsigned short Bs[2][8192];   // 2 x (32 cols x 256 k)
    __shared__ float mbuf[4][2][16][8];                    // [rs*2+s][half][m16][q]
    const int t = threadIdx.x;
    const int cs = blockIdx.x;
    const int r0 = blockIdx.y * 64;
    const int w = t >> 6, lid = t & 63, g = lid >> 4, m16 = lid & 15;
    const int rs = w >> 1, ch = w & 1;

    short8 bfr[2][8];   // eh B-frags: rows r0+rs*32+s*16+m16, k = ks*32 + g*8 + j
    #pragma unroll
    for (int s = 0; s < 2; s++)
        #pragma unroll
        for (int ks = 0; ks < 8; ks++)
            bfr[s][ks] = *(const short8*)
                &eh16[(size_t)(r0 + rs * 32 + s * 16 + m16) * 256 + ks * 32 + g * 8];

    float tk0[6], tk1[6];
    #pragma unroll
    for (int q = 0; q < 6; q++) { tk0[q] = -3.0e38f; tk1[q] = -3.0e38f; }

    // staging map (verbatim R12/R16): chunk = w*4+c; linear LDS granule L holds
    // (col = L>>5, gorig = (gs&24)|((gs^col)&7)), gs = L&31.
    int scol[4], goff[4], ldsl[4];
    #pragma unroll
    for (int c = 0; c < 4; c++) {
        int L = (w * 4 + c) * 64 + lid;
        int col = L >> 5, gs = L & 31;
        int gorig = (gs & 24) | ((gs ^ col) & 7);
        scol[c] = col; goff[c] = gorig * 8; ldsl[c] = L * 8;
    }

    #pragma unroll
    for (int c = 0; c < 4; c++)
        gload_lds16(&et16[(size_t)(cs * 2048 + scol[c]) * 256 + goff[c]], &Bs[0][ldsl[c]]);
    __syncthreads();

    const int swz = m16 & 7;
    const int cbase = (ch * 16 + m16) * 32;   // this wave's col-half, lane's col row
    for (int tile = 0; tile < 64; tile++) {
        const int cur = tile & 1;
        if (tile + 1 < 64) {
            const int j1 = cs * 2048 + (tile + 1) * 32;
            #pragma unroll
            for (int c = 0; c < 4; c++)
                gload_lds16(&et16[(size_t)(j1 + scol[c]) * 256 + goff[c]],
                            &Bs[cur ^ 1][ldsl[c]]);
        }
        f32x4 a0 = {0.0f, 0.0f, 0.0f, 0.0f}, a1 = a0;
        #pragma unroll
        for (int ks = 0; ks < 8; ks++) {
            const int gq = ks * 4 + g;
            short8 e = *(const short8*)&Bs[cur][(cbase + (gq ^ swz)) * 8];
            a0 = mfma16(e, bfr[0][ks], a0);   // A = et (LDS), B = eh (regs)
            a1 = mfma16(e, bfr[1][ks], a1);
        }
        const unsigned cb = (unsigned)(tile * 32 + ch * 16 + g * 4);
        #pragma unroll
        for (int r = 0; r < 4; r++) {
            insf<6>(tk0, packkey(a0[r], cb + (unsigned)r));
            insf<6>(tk1, packkey(a1[r], cb + (unsigned)r));
        }
        __syncthreads();
    }

    // per row-set: widen to 8 (sentinels), butterfly over the 4 g-lanes, stash
    #pragma unroll
    for (int s = 0; s < 2; s++) {
        float tk8[8];
        tk8[0] = -3.0e38f; tk8[1] = -3.0e38f;
        #pragma unroll
        for (int q = 0; q < 6; q++) tk8[q + 2] = s ? tk1[q] : tk0[q];
        #pragma unroll
        for (int step = 16; step <= 32; step <<= 1) {
            float ok[8];
            #pragma unroll
            for (int q = 0; q < 8; q++) ok[q] = __shfl_xor(tk8[q], step);
            #pragma unroll
            for (int q = 0; q < 8; q++) insf<8>(tk8, ok[q]);
        }
        if (g == 0) {
            #pragma unroll
            for (int q = 0; q < 8; q++) mbuf[rs * 2 + s][ch][m16][q] = tk8[q];
        }
    }
    __syncthreads();

    // cross-half merge: thread t (<64) owns row r0+t; both halves' lists sorted.
    if (t < 64) {
        float tk8[8];
        #pragma unroll
        for (int q = 0; q < 8; q++) tk8[q] = mbuf[t >> 4][0][t & 15][q];
        #pragma unroll
        for (int q = 0; q < 8; q++) insf<8>(tk8, mbuf[t >> 4][1][t & 15][q]);
        const int row = r0 + t;
        #pragma unroll
        for (int q = 0; q < 8; q++)
            candi[(size_t)row * 32 + cs * 8 + q] =
                cs * 2048 + (int)(__builtin_bit_cast(unsigned, tk8[q]) & 0x7FFu);
    }
}

// ---------------------------------------------------------------------------
// Stage D (proven R13): LDS-free, barrier-free. 4 waves/block, one row per wave.
// ---------------------------------------------------------------------------
__launch_bounds__(256)
__global__ void stageD(const float* __restrict__ eh, const float* __restrict__ et,
                       const float* __restrict__ rowsum,
                       const int* __restrict__ candi,
                       unsigned short* __restrict__ m1, unsigned short* __restrict__ m2) {
    const int w = threadIdx.x >> 6, l = threadIdx.x & 63;
    const int i = blockIdx.x * 4 + w;

    const int jown = candi[(size_t)i * 32 + (l & 31)] & 8191;

    const int c = l >> 1, h = l & 1;
    const int jc = __shfl(jown, c);
    const float* eprow = &eh[(size_t)i * 256 + h * 128];
    const float* etrow = &et[(size_t)jc * 256 + h * 128];
    double acc = 0.0, acc2 = 0.0;
    #pragma unroll 4
    for (int q = 0; q < 32; q += 2) {
        f32x4 a0 = *(const f32x4*)&eprow[q * 4];
        f32x4 b0 = *(const f32x4*)&etrow[q * 4];
        f32x4 a1 = *(const f32x4*)&eprow[q * 4 + 4];
        f32x4 b1 = *(const f32x4*)&etrow[q * 4 + 4];
        acc  += (double)a0[0] * b0[0] + (double)a0[1] * b0[1] +
                (double)a0[2] * b0[2] + (double)a0[3] * b0[3];
        acc2 += (double)a1[0] * b1[0] + (double)a1[1] * b1[1] +
                (double)a1[2] * b1[2] + (double)a1[3] * b1[3];
    }
    double p = acc + acc2;
    p += __shfl_xor(p, 1);
    p *= 0.0625;

    double v = __shfl(p, 2 * (l & 31));

    float wf[6]; int selj[6];
    #pragma unroll
    for (int s = 0; s < 6; s++) {
        double bv = v; int bj = jown;
        #pragma unroll
        for (int st = 1; st < 64; st <<= 1) {
            double ov = __shfl_xor(bv, st);
            int oj = __shfl_xor(bj, st);
            bool take = (ov > bv) || (ov == bv && oj < bj);
            bv = take ? ov : bv;
            bj = take ? oj : bj;
        }
        wf[s] = (float)bv; selj[s] = bj;
        if (jown == bj) v = -1.0e300;
    }

    float sp[6];
    {
        float mx = wf[0];
        #pragma unroll
        for (int s = 1; s < 6; s++) mx = fmaxf(mx, wf[s]);
        float se = 0.0f, e6[6];
        #pragma unroll
        for (int s = 0; s < 6; s++) { e6[s] = expf(wf[s] - mx); se += e6[s]; }
        #pragma unroll
        for (int s = 0; s < 6; s++) sp[s] = e6[s] / se;
    }

    f32x4 eh4 = *(const f32x4*)&eh[(size_t)i * 256 + l * 4];
    f32x4 nb[6];
    #pragma unroll
    for (int k = 0; k < 6; k++)
        nb[k] = *(const f32x4*)&et[(size_t)selj[k] * 256 + l * 4];

    float pgs[6], pns[6];
    #pragma unroll
    for (int k = 0; k < 6; k++) {
        const float pk = sp[k];
        float pg = 0.0f;
        #pragma unroll
        for (int e = 0; e < 4; e++) {
            float ehd = eh4[e], nbd = nb[k][e];
            float ehr = pk * nbd + (1.0f - pk) * ehd;
            pg += tanhf(ehd + ehr);
        }
        #pragma unroll
        for (int st = 1; st < 64; st <<= 1) pg += __shfl_xor(pg, st);
        pgs[k] = pg;
        pns[k] = rowsum[selj[k]];
    }

    float skp[6];
    {
        float ka[6], mx = -3.0e38f, se = 0.0f;
        #pragma unroll
        for (int k = 0; k < 6; k++) { ka[k] = pns[k] * pgs[k]; mx = fmaxf(mx, ka[k]); }
        #pragma unroll
        for (int k = 0; k < 6; k++) { ka[k] = expf(ka[k] - mx); se += ka[k]; }
        #pragma unroll
        for (int k = 0; k < 6; k++) skp[k] = ka[k] / se;
    }

    f32x4 enh = {0.0f, 0.0f, 0.0f, 0.0f};
    #pragma unroll
    for (int k = 0; k < 6; k++) {
        const float kp = skp[k];
        #pragma unroll
        for (int e = 0; e < 4; e++) enh[e] += kp * nb[k][e];
    }
    short4v h1, h2;
    #pragma unroll
    for (int e = 0; e < 4; e++) {
        h1[e] = (short)f2bf(eh4[e] + enh[e]);
        h2[e] = (short)f2bf(eh4[e] * enh[e]);
    }
    *(short4v*)&m1[(size_t)i * 256 + l * 4] = h1;
    *(short4v*)&m2[(size_t)i * 256 + l * 4] = h2;
}

// ---------------------------------------------------------------------------
__launch_bounds__(256)
__global__ void gate2_k(const float* __restrict__ g1, const float* __restrict__ Ag2,
                        const float* __restrict__ bg2, float* __restrict__ glog) {
    const int i = blockIdx.x * 256 + threadIdx.x;
    float s = 0.0f;
    #pragma unroll 4
    for (int h = 0; h < 128; h++) s += g1[(size_t)i * 128 + h] * Ag2[h];
    glog[i] = s + bg2[0];
}

__launch_bounds__(1024)
__global__ void softmax_g(const float* __restrict__ glog, float* __restrict__ gexp,
                          float* __restrict__ scal) {
    const int t = threadIdx.x;
    __shared__ float red[1024];
    float v[8];
    float m = -3.0e38f;
    #pragma unroll
    for (int c = 0; c < 8; c++) { v[c] = glog[t + c * 1024]; m = fmaxf(m, v[c]); }
    red[t] = m; __syncthreads();
    for (int st = 512; st > 0; st >>= 1) {
        if (t < st) red[t] = fmaxf(red[t], red[t + st]);
        __syncthreads();
    }
    float gm = red[0]; __syncthreads();
    float s = 0.0f;
    #pragma unroll
    for (int c = 0; c < 8; c++) {
        float e = expf(v[c] - gm);
        gexp[t + c * 1024] = e;
        s += e;
    }
    red[t] = s; __syncthreads();
    for (int st = 512; st > 0; st >>= 1) {
        if (t < st) red[t] += red[t + st];
        __syncthreads();
    }
    if (t == 0) scal[0] = 1.0f / red[0];
}

__launch_bounds__(256)
__global__ void wsum_k(const float* __restrict__ emsg, const float* __restrict__ gexp,
                       float* __restrict__ egp) {
    const int b = blockIdx.x, d = threadIdx.x;
    float s = 0.0f;
    const int i0 = b * 128;
    for (int i = 0; i < 128; i++) s += gexp[i0 + i] * emsg[(size_t)(i0 + i) * 256 + d];
    egp[b * 256 + d] = s;
}
__global__ void egfinal_f(const float* __restrict__ egp, const float* __restrict__ scal,
                          float* __restrict__ out) {
    const int d = threadIdx.x;
    float s = 0.0f;
    for (int b = 0; b < 64; b++) s += egp[b * 256 + d];
    out[d] = s * scal[0];
}

__global__ void wsbad_k(float* __restrict__ out) { out[3] = 9000.0f; }

// ---------------------------------------------------------------------------
extern "C" void kernel_launch(void* const* d_in, const int* in_sizes, int n_in,
                              void* d_out, int out_size, void* d_ws, size_t ws_size,
                              hipStream_t stream) {
    (void)in_sizes; (void)n_in; (void)out_size;
    const float* x_path = (const float*)d_in[0];
    const float* fc1_W  = (const float*)d_in[1];
    const float* fc1_b  = (const float*)d_in[2];
    const float* Wh     = (const float*)d_in[3];
    const float* bh     = (const float*)d_in[4];
    const float* Wt     = (const float*)d_in[5];
    const float* bt     = (const float*)d_in[6];
    const float* W1     = (const float*)d_in[7];
    const float* b1     = (const float*)d_in[8];
    const float* W2     = (const float*)d_in[9];
    const float* b2     = (const float*)d_in[10];
    const float* Ag1    = (const float*)d_in[11];
    const float* bg1    = (const float*)d_in[12];
    const float* Ag2    = (const float*)d_in[13];
    const float* bg2    = (const float*)d_in[14];
    float* out_f = (float*)d_out;   // fp32: e_msg [0,2097152), e_g [2097152,2097408)

    const size_t WS_NEEDED = 26412048;
    if (ws_size < WS_NEEDED) {
        hipLaunchKernelGGL(wsbad_k, dim3(1), dim3(1), 0, stream, out_f);
        return;
    }

    char* ws = (char*)d_ws;
    float* x     = (float*)(ws + 0);
    unsigned short* eh16 = (unsigned short*)(ws + 0);
    unsigned short* et16 = (unsigned short*)(ws + 4194304);
    unsigned short* m1b  = (unsigned short*)(ws + 0);
    unsigned short* m2b  = (unsigned short*)(ws + 4194304);
    float* g1    = (float*)(ws + 0);          // 8192x128 fp32 (after m1b/m2b dead)
    float* eh    = (float*)(ws + 8388608);
    float* emsg  = out_f;                     // e_msg written straight to d_out
    float* et    = (float*)(ws + 16777216);
    int*   candi = (int*)  (ws + 25165824);
    float* rowsum= (float*)(ws + 26214400);   // meanp slot (dead after meanred)
    float* meanp = (float*)(ws + 26214400);
    float* meanv = (float*)(ws + 26279936);
    float* glog  = (float*)(ws + 26280960);
    float* gexp  = (float*)(ws + 26313728);
    float* egp   = (float*)(ws + 26346496);
    float* scal  = (float*)(ws + 26412032);

    // weight planes in temporarily-dead regions (all stream-ordered safe):
    unsigned short* Fp = (unsigned short*)(ws + 16777216);   // fc1, in et region
    unsigned short* WHp = (unsigned short*)(ws + 25165824);  // in candi region
    unsigned short* WTp = (unsigned short*)(ws + 25559040);
    unsigned short* P1 = (unsigned short*)(ws + 16777216);   // in et region (post-stageD)
    unsigned short* P2 = (unsigned short*)(ws + 17170432);
    unsigned short* Gp = (unsigned short*)(ws + 25165824);   // in candi region (post-stageD)

    dim3 gg(4, 128);
    // 1) x = leaky(x_path @ fc1_W + fc1_b)  [MFMA 3-split]
    hipLaunchKernelGGL(tsplit3, dim3(8, 32), dim3(256), 0, stream,
                       fc1_W, Fp, 1024, 256, 262144);
    hipLaunchKernelGGL((gemmM<1, 1, 0>), gg, dim3(256), 0, stream,
                       (const void*)x_path, Fp, fc1_b, x, 256, 1024, 262144);
    // 2) x = (x + mean(x)) * 0.5
    hipLaunchKernelGGL(colsum_k, dim3(64), dim3(256), 0, stream, x, meanp);
    hipLaunchKernelGGL(meanred_k, dim3(1), dim3(256), 0, stream, meanp, meanv);
    hipLaunchKernelGGL(finalize_x, dim3(2048), dim3(256), 0, stream, x, meanv);
    // 3) e_h, e_t  [MFMA 3-split, fp32-accurate]
    hipLaunchKernelGGL(tsplit3, dim3(8, 8), dim3(256), 0, stream,
                       Wh, WHp, 256, 256, 65536);
    hipLaunchKernelGGL(tsplit3, dim3(8, 8), dim3(256), 0, stream,
                       Wt, WTp, 256, 256, 65536);
    hipLaunchKernelGGL((gemmM<1, 0, 0>), gg, dim3(256), 0, stream,
                       (const void*)x, WHp, bh, eh, 256, 256, 65536);
    hipLaunchKernelGGL((gemmM<1, 0, 0>), gg, dim3(256), 0, stream,
                       (const void*)x, WTp, bt, et, 256, 256, 65536);
    // 4) bf16 copies for screening + et row sums
    hipLaunchKernelGGL(f2bf_k, dim3(2048), dim3(256), 0, stream, eh, eh16, 524288);
    hipLaunchKernelGGL(f2bf_k, dim3(2048), dim3(256), 0, stream, et, et16, 524288);
    hipLaunchKernelGGL(rowsum_k, dim3(2048), dim3(256), 0, stream, et, rowsum);
    // 5) screening: 64 rows/block, wave = rowset x col-half, 2 blocks/CU
    hipLaunchKernelGGL(screen2, dim3(4, 128), dim3(256), 0, stream, eh16, et16, candi);
    // 6) fp64 select + message -> m1b/m2b
    hipLaunchKernelGGL(stageD, dim3(2048), dim3(256), 0, stream, eh, et, rowsum,
                       candi, m1b, m2b);
    // 7) e_msg = leaky(m1@W1+b1) + leaky(m2@W2+b2)  -> straight into out_f
    hipLaunchKernelGGL(tsplit3, dim3(8, 8), dim3(256), 0, stream,
                       W1, P1, 256, 256, 65536);
    hipLaunchKernelGGL(tsplit3, dim3(8, 8), dim3(256), 0, stream,
                       W2, P2, 256, 256, 65536);
    hipLaunchKernelGGL((gemmM<0, 1, 0>), gg, dim3(256), 0, stream,
                       (const void*)m1b, P1, b1, emsg, 256, 256, 65536);
    hipLaunchKernelGGL((gemmM<0, 1, 1>), gg, dim3(256), 0, stream,
                       (const void*)m2b, P2, b2, emsg, 256, 256, 65536);
    // 8) readout: g1 = leaky(emsg@Ag1+bg1) [MFMA 3-split]; then small ops
    hipLaunchKernelGGL(tsplit3, dim3(4, 8), dim3(256), 0, stream,
                       Ag1, Gp, 256, 128, 32768);
    hipLaunchKernelGGL((gemmM<1, 1, 0>), dim3(2, 128), dim3(256), 0, stream,
                       (const void*)emsg, Gp, bg1, g1, 128, 256, 32768);
    hipLaunchKernelGGL(gate2_k, dim3(32), dim3(256), 0, stream, g1, Ag2, bg2, glog);
    hipLaunchKernelGGL(softmax_g, dim3(1), dim3(1024), 0, stream, glog, gexp, scal);
    hipLaunchKernelGGL(wsum_k, dim3(64), dim3(256), 0, stream, emsg, gexp, egp);
    hipLaunchKernelGGL(egfinal_f, dim3(1), dim3(256), 0, stream, egp, scal, out_f + 2097152);
}

// Round 8
// 362.858 us; speedup vs baseline: 1.0417x; 1.0417x over previous
//
#include <hip/hip_runtime.h>

// MOTCAT_Surv R18. R17 REGRESSED (73.5 us vs R16 66.5; total 378): 2 blocks/CU
// doubled per-CU staging writes AND barrier-chain count; both R16/R17 run ~3x
// their LDS floor -- the wall is the exposed vmcnt(0) drain at each per-tile
// barrier (loads have <1 tile of compute to land). R18: one 512-thr block/CU
// (grid (4,64), 8 waves = 2/SIMD): wave = rowset (w>>1, 32 rows) x col-half
// (w&1). Staging once per CU (16KB/tile, as R16) + R17's 8KB/wave reads.
// 2-tile groups double-buffered (64KB LDS): ONE barrier per 2 tiles (32 total)
// and next-group loads issued at group start get a full 2-tile compute phase
// (~1200cyc) to cover L2 (~600cyc) -> drain finds them landed. Tile layout,
// swizzle, med3 top-k, merge tree verbatim R17. Everything else = R17 (proven).

typedef __attribute__((ext_vector_type(8))) short short8;
typedef __attribute__((ext_vector_type(4))) short short4v;
typedef __attribute__((ext_vector_type(4))) float f32x4;

__device__ inline float bf2f(unsigned short b) {
    unsigned u = ((unsigned)b) << 16;
    return __builtin_bit_cast(float, u);
}
__device__ inline unsigned short f2bf(float f) {   // round-to-nearest-even
    unsigned u = __builtin_bit_cast(unsigned, f);
    unsigned r = u + 0x7fffu + ((u >> 16) & 1u);
    return (unsigned short)(r >> 16);
}
__device__ inline f32x4 mfma16(short8 a, short8 b, f32x4 c) {
    return __builtin_amdgcn_mfma_f32_16x16x32_bf16(a, b, c, 0, 0, 0);
}
// A-frag: lane holds A[m=lane&15][k=(lane>>4)*8+j]; B-frag: B[k][n=lane&15];
// C/D: col=lane&15 (n), row=(lane>>4)*4+reg (m) (learn_hip m89).

__device__ inline void gload_lds16(const unsigned short* g, unsigned short* l) {
    __builtin_amdgcn_global_load_lds(
        (const __attribute__((address_space(1))) void*)g,
        (__attribute__((address_space(3))) void*)l, 16, 0, 0);
}

// split fp32 -> bf16 hi/mid/lo (residual subtractions are exact: operands close)
__device__ inline void split8(const f32x4 v0, const f32x4 v1,
                              short8& hi, short8& md, short8& lo) {
    #pragma unroll
    for (int e = 0; e < 8; e++) {
        float a = (e < 4) ? v0[e] : v1[e - 4];
        unsigned short h = f2bf(a);
        float r1 = a - bf2f(h);
        unsigned short m = f2bf(r1);
        float r2 = r1 - bf2f(m);
        unsigned short l = f2bf(r2);
        hi[e] = (short)h; md[e] = (short)m; lo[e] = (short)l;
    }
}

// ---------------------------------------------------------------------------
// tsplit3: W [K][N] fp32 -> Bt planes [n][k] bf16 (hi, mid, lo) at out + p*PS.
// ---------------------------------------------------------------------------
__launch_bounds__(256)
__global__ void tsplit3(const float* __restrict__ W, unsigned short* __restrict__ out,
                        int K, int N, int PS) {
    __shared__ float T[32][33];
    const int t = threadIdx.x;
    const int n0 = blockIdx.x * 32, k0 = blockIdx.y * 32;
    {
        const int r = t >> 3, c = (t & 7) * 4;
        f32x4 v = *(const f32x4*)&W[(size_t)(k0 + r) * N + n0 + c];
        #pragma unroll
        for (int e = 0; e < 4; e++) T[r][c + e] = v[e];
    }
    __syncthreads();
    const int nr = t >> 3, kc = (t & 7) * 4;
    short4v h4, m4, l4;
    #pragma unroll
    for (int e = 0; e < 4; e++) {
        float a = T[kc + e][nr];
        unsigned short h = f2bf(a);
        float r1 = a - bf2f(h);
        unsigned short m = f2bf(r1);
        float r2 = r1 - bf2f(m);
        h4[e] = (short)h; m4[e] = (short)m; l4[e] = (short)f2bf(r2);
    }
    const size_t o = (size_t)(n0 + nr) * K + k0 + kc;
    *(short4v*)&out[o] = h4;
    *(short4v*)&out[(size_t)PS + o] = m4;
    *(short4v*)&out[(size_t)2 * PS + o] = l4;
}

// ---------------------------------------------------------------------------
// gemmM (proven R15): C = act(A@B + bias) (+=C if ACCUM) on matrix cores.
// ---------------------------------------------------------------------------
template <int ASPLIT, int ACT, int ACCUM>
__launch_bounds__(256)
__global__ void gemmM(const void* __restrict__ Av,
                      const unsigned short* __restrict__ Bt,
                      const float* __restrict__ bias, float* __restrict__ C,
                      int N, int K, int BPS) {
    constexpr int APL = ASPLIT ? 3 : 1;
    constexpr int BPL = ASPLIT ? 3 : 2;
    __shared__ __align__(16) unsigned short LA[2][APL * 2048];
    __shared__ __align__(16) unsigned short LB[2][BPL * 2048];
    const int t = threadIdx.x;
    const int r0 = blockIdx.y * 64, c0 = blockIdx.x * 64;
    const int lid = t & 63, w = t >> 6, g = lid >> 4, m16 = lid & 15;
    const int wm = w >> 1, wn = w & 1;

    f32x4 acc[2][2];
    #pragma unroll
    for (int mf = 0; mf < 2; mf++)
        #pragma unroll
        for (int nf = 0; nf < 2; nf++) acc[mf][nf] = {0.0f, 0.0f, 0.0f, 0.0f};

    const int KT = K >> 5;
    const size_t aoff = (size_t)(r0 + (t >> 2)) * K + (t & 3) * 8;
    const size_t boff = (size_t)(c0 + (t >> 2)) * K + (t & 3) * 8;

    {
        #pragma unroll
        for (int p = 0; p < BPL; p++)
            gload_lds16(&Bt[(size_t)p * BPS + boff], &LB[0][p * 2048 + 8 * t]);
        if (ASPLIT) {
            const float* A = (const float*)Av;
            f32x4 v0 = *(const f32x4*)&A[aoff];
            f32x4 v1 = *(const f32x4*)&A[aoff + 4];
            short8 hi, md, lo;
            split8(v0, v1, hi, md, lo);
            *(short8*)&LA[0][8 * t] = hi;
            *(short8*)&LA[0][2048 + 8 * t] = md;
            *(short8*)&LA[0][4096 + 8 * t] = lo;
        } else {
            const unsigned short* A16 = (const unsigned short*)Av;
            gload_lds16(&A16[aoff], &LA[0][8 * t]);
        }
    }
    __syncthreads();

    for (int kt = 0; kt < KT; kt++) {
        const int cur = kt & 1, nxt = cur ^ 1;
        const bool hn = (kt + 1) < KT;
        f32x4 v0, v1;
        if (hn) {
            const size_t ko = (size_t)(kt + 1) * 32;
            #pragma unroll
            for (int p = 0; p < BPL; p++)
                gload_lds16(&Bt[(size_t)p * BPS + boff + ko],
                            &LB[nxt][p * 2048 + 8 * t]);
            if (ASPLIT) {
                const float* A = (const float*)Av;
                v0 = *(const f32x4*)&A[aoff + ko];
                v1 = *(const f32x4*)&A[aoff + ko + 4];
            } else {
                const unsigned short* A16 = (const unsigned short*)Av;
                gload_lds16(&A16[aoff + ko], &LA[nxt][8 * t]);
            }
        }
        short8 af[2][APL], bf[2][BPL];
        #pragma unroll
        for (int mf = 0; mf < 2; mf++) {
            const int row = wm * 32 + mf * 16 + m16;
            #pragma unroll
            for (int p = 0; p < APL; p++)
                af[mf][p] = *(const short8*)&LA[cur][p * 2048 + row * 32 + g * 8];
        }
        #pragma unroll
        for (int nf = 0; nf < 2; nf++) {
            const int col = wn * 32 + nf * 16 + m16;
            #pragma unroll
            for (int p = 0; p < BPL; p++)
                bf[nf][p] = *(const short8*)&LB[cur][p * 2048 + col * 32 + g * 8];
        }
        #pragma unroll
        for (int mf = 0; mf < 2; mf++)
            #pragma unroll
            for (int nf = 0; nf < 2; nf++) {
                if (ASPLIT) {
                    acc[mf][nf] = mfma16(af[mf][0], bf[nf][0], acc[mf][nf]); // hh
                    acc[mf][nf] = mfma16(af[mf][0], bf[nf][1], acc[mf][nf]); // hm
                    acc[mf][nf] = mfma16(af[mf][1], bf[nf][0], acc[mf][nf]); // mh
                    acc[mf][nf] = mfma16(af[mf][0], bf[nf][2], acc[mf][nf]); // hl
                    acc[mf][nf] = mfma16(af[mf][1], bf[nf][1], acc[mf][nf]); // mm
                    acc[mf][nf] = mfma16(af[mf][2], bf[nf][0], acc[mf][nf]); // lh
                } else {
                    acc[mf][nf] = mfma16(af[mf][0], bf[nf][0], acc[mf][nf]);
                    acc[mf][nf] = mfma16(af[mf][0], bf[nf][1], acc[mf][nf]);
                }
            }
        if (hn && ASPLIT) {
            short8 hi, md, lo;
            split8(v0, v1, hi, md, lo);
            *(short8*)&LA[nxt][8 * t] = hi;
            *(short8*)&LA[nxt][2048 + 8 * t] = md;
            *(short8*)&LA[nxt][4096 + 8 * t] = lo;
        }
        __syncthreads();
    }

    #pragma unroll
    for (int nf = 0; nf < 2; nf++) {
        const int col = c0 + wn * 32 + nf * 16 + m16;
        const float bv = bias[col];
        #pragma unroll
        for (int mf = 0; mf < 2; mf++) {
            #pragma unroll
            for (int r = 0; r < 4; r++) {
                const int row = r0 + wm * 32 + mf * 16 + g * 4 + r;
                float v = acc[mf][nf][r] + bv;
                if (ACT == 1) v = v > 0.0f ? v : 0.01f * v;
                size_t idx = (size_t)row * N + col;
                if (ACCUM) v += C[idx];
                C[idx] = v;
            }
        }
    }
}

// ---------------------------------------------------------------------------
__global__ void colsum_k(const float* __restrict__ x, float* __restrict__ out) {
    int d = threadIdx.x, b = blockIdx.x;
    float s = 0.0f;
    int i0 = b * 128;
    for (int i = 0; i < 128; i++) s += x[(size_t)(i0 + i) * 256 + d];
    out[b * 256 + d] = s;
}
__global__ void meanred_k(const float* __restrict__ p, float* __restrict__ mean) {
    int d = threadIdx.x;
    float s = 0.0f;
    for (int b = 0; b < 64; b++) s += p[b * 256 + d];
    mean[d] = s * (1.0f / 8192.0f);
}
__global__ void finalize_x(float* __restrict__ x, const float* __restrict__ mean) {
    size_t idx = (size_t)blockIdx.x * blockDim.x + threadIdx.x;
    f32x4 v = *(f32x4*)&x[idx * 4];
    int d4 = (int)((idx * 4) & 255);
    f32x4 m = *(const f32x4*)&mean[d4];
    #pragma unroll
    for (int e = 0; e < 4; e++) v[e] = (v[e] + m[e]) * 0.5f;
    *(f32x4*)&x[idx * 4] = v;
}
__global__ void f2bf_k(const float* __restrict__ src, unsigned short* __restrict__ dst, int n4) {
    size_t idx = (size_t)blockIdx.x * blockDim.x + threadIdx.x;
    if (idx >= (size_t)n4) return;
    f32x4 v = *(const f32x4*)&src[idx * 4];
    short4v h;
    #pragma unroll
    for (int e = 0; e < 4; e++) h[e] = (short)f2bf(v[e]);
    *(short4v*)&dst[idx * 4] = h;
}
// rowsum[i] = sum_d et[i][d]
__launch_bounds__(256)
__global__ void rowsum_k(const float* __restrict__ et, float* __restrict__ rowsum) {
    const int w = threadIdx.x >> 6, l = threadIdx.x & 63;
    const int i = blockIdx.x * 4 + w;
    f32x4 v = *(const f32x4*)&et[(size_t)i * 256 + l * 4];
    float s = v[0] + v[1] + v[2] + v[3];
    #pragma unroll
    for (int st = 1; st < 64; st <<= 1) s += __shfl_xor(s, st);
    if (l == 0) rowsum[i] = s;
}

// ---------------------------------------------------------------------------
// float keys (col in low-11 mantissa bits), med3 insert. Ascending, tk[0]=min.
// ---------------------------------------------------------------------------
__device__ inline float packkey(float v, unsigned col) {
    unsigned u = (__builtin_bit_cast(unsigned, v) & 0xFFFFF800u) | col;
    return __builtin_bit_cast(float, u);
}
template<int NK>
__device__ inline void insf(float (&tk)[NK], float key) {
    #pragma unroll
    for (int k = 0; k < NK - 1; k++)
        tk[k] = __builtin_amdgcn_fmed3f(key, tk[k + 1], tk[k]);
    tk[NK - 1] = fmaxf(tk[NK - 1], key);
}

// ---------------------------------------------------------------------------
// screen2 R18: 512 thr = 8 waves, block = 128 rows, grid (4,64) = 1 block/CU
// (2 waves/SIMD). Wave w: rowset rs=w>>1 (32 rows, 2 bfr sets) x col-half
// ch=w&1 (16 of 32 tile cols). Staging: 2-tile groups (32KB), double-buffered;
// each thread stages 2 granules/tile (same XOR-swizzle map); next-group loads
// issued at group start -> full 2-tile compute covers L2 latency; ONE barrier
// per group (32 total). Per wave/tile: 8 swizzled ds_read_b128, 16 MFMA,
// 8 med3 inserts. End: g-butterfly top-8/half -> mbuf -> 128-thread cross-half
// merge -> candi top-8/quarter/row.
// ---------------------------------------------------------------------------
__launch_bounds__(512)
__global__ void screen2(const unsigned short* __restrict__ eh16,
                        const unsigned short* __restrict__ et16,
                        int* __restrict__ candi) {
    __shared__ __align__(16) unsigned short Bs[2][2][8192];  // [buf][tile-in-group]
    __shared__ float mbuf[8][2][16][8];                      // [rowgrp][half][m16][q]
    const int t = threadIdx.x;
    const int cs = blockIdx.x;
    const int r0 = blockIdx.y * 128;
    const int w = t >> 6, lid = t & 63, lg = lid >> 4, m16 = lid & 15;
    const int rs = w >> 1, ch = w & 1;

    short8 bfr[2][8];   // eh B-frags: rows r0+rs*32+s*16+m16, k = ks*32 + lg*8 + j
    #pragma unroll
    for (int s = 0; s < 2; s++)
        #pragma unroll
        for (int ks = 0; ks < 8; ks++)
            bfr[s][ks] = *(const short8*)
                &eh16[(size_t)(r0 + rs * 32 + s * 16 + m16) * 256 + ks * 32 + lg * 8];

    float tk0[6], tk1[6];
    #pragma unroll
    for (int q = 0; q < 6; q++) { tk0[q] = -3.0e38f; tk1[q] = -3.0e38f; }

    // staging map: per tile, thread stages 2 granules c=0,1: linear granule
    // L = (w*2+c)*64 + lid in [0,1024); L holds (col = L>>5,
    // gorig = (gs&24)|((gs^col)&7)), gs = L&31  (XOR-swizzle, verbatim R12/R16/R17)
    int scol[2], goff[2], ldsl[2];
    #pragma unroll
    for (int c = 0; c < 2; c++) {
        int L = (w * 2 + c) * 64 + lid;
        int col = L >> 5, gs = L & 31;
        int gorig = (gs & 24) | ((gs ^ col) & 7);
        scol[c] = col; goff[c] = gorig * 8; ldsl[c] = L * 8;
    }

    // prologue: stage group 0 (tiles 0,1) into buf 0
    #pragma unroll
    for (int tt = 0; tt < 2; tt++) {
        const int j0 = cs * 2048 + tt * 32;
        #pragma unroll
        for (int c = 0; c < 2; c++)
            gload_lds16(&et16[(size_t)(j0 + scol[c]) * 256 + goff[c]],
                        &Bs[0][tt][ldsl[c]]);
    }
    __syncthreads();

    const int swz = m16 & 7;
    const int cbase = (ch * 16 + m16) * 32;   // this wave's col-half, lane's col
    for (int gi = 0; gi < 32; gi++) {
        const int cur = gi & 1;
        if (gi + 1 < 32) {   // issue next group's loads first (overlap compute)
            #pragma unroll
            for (int tt = 0; tt < 2; tt++) {
                const int j1 = cs * 2048 + ((gi + 1) * 2 + tt) * 32;
                #pragma unroll
                for (int c = 0; c < 2; c++)
                    gload_lds16(&et16[(size_t)(j1 + scol[c]) * 256 + goff[c]],
                                &Bs[cur ^ 1][tt][ldsl[c]]);
            }
        }
        #pragma unroll
        for (int tt = 0; tt < 2; tt++) {
            const int tile = gi * 2 + tt;
            const unsigned short* bst = Bs[cur][tt];
            f32x4 a0 = {0.0f, 0.0f, 0.0f, 0.0f}, a1 = a0;
            #pragma unroll
            for (int ks = 0; ks < 8; ks++) {
                const int gq = ks * 4 + lg;
                short8 e = *(const short8*)&bst[(cbase + (gq ^ swz)) * 8];
                a0 = mfma16(e, bfr[0][ks], a0);   // A = et (LDS), B = eh (regs)
                a1 = mfma16(e, bfr[1][ks], a1);
            }
            const unsigned cb = (unsigned)(tile * 32 + ch * 16 + lg * 4);
            #pragma unroll
            for (int r = 0; r < 4; r++) {
                insf<6>(tk0, packkey(a0[r], cb + (unsigned)r));
                insf<6>(tk1, packkey(a1[r], cb + (unsigned)r));
            }
        }
        __syncthreads();   // next group landed; reads of buf cur done
    }

    // per row-set: widen to 8 (sentinels), butterfly over the 4 lg-lanes, stash
    #pragma unroll
    for (int s = 0; s < 2; s++) {
        float tk8[8];
        tk8[0] = -3.0e38f; tk8[1] = -3.0e38f;
        #pragma unroll
        for (int q = 0; q < 6; q++) tk8[q + 2] = s ? tk1[q] : tk0[q];
        #pragma unroll
        for (int step = 16; step <= 32; step <<= 1) {
            float ok[8];
            #pragma unroll
            for (int q = 0; q < 8; q++) ok[q] = __shfl_xor(tk8[q], step);
            #pragma unroll
            for (int q = 0; q < 8; q++) insf<8>(tk8, ok[q]);
        }
        if (lg == 0) {
            #pragma unroll
            for (int q = 0; q < 8; q++) mbuf[rs * 2 + s][ch][m16][q] = tk8[q];
        }
    }
    __syncthreads();

    // cross-half merge: thread t (<128) owns row r0+t; both halves' lists sorted.
    if (t < 128) {
        float tk8[8];
        #pragma unroll
        for (int q = 0; q < 8; q++) tk8[q] = mbuf[t >> 4][0][t & 15][q];
        #pragma unroll
        for (int q = 0; q < 8; q++) insf<8>(tk8, mbuf[t >> 4][1][t & 15][q]);
        const int row = r0 + t;
        #pragma unroll
        for (int q = 0; q < 8; q++)
            candi[(size_t)row * 32 + cs * 8 + q] =
                cs * 2048 + (int)(__builtin_bit_cast(unsigned, tk8[q]) & 0x7FFu);
    }
}

// ---------------------------------------------------------------------------
// Stage D (proven R13): LDS-free, barrier-free. 4 waves/block, one row per wave.
// ---------------------------------------------------------------------------
__launch_bounds__(256)
__global__ void stageD(const float* __restrict__ eh, const float* __restrict__ et,
                       const float* __restrict__ rowsum,
                       const int* __restrict__ candi,
                       unsigned short* __restrict__ m1, unsigned short* __restrict__ m2) {
    const int w = threadIdx.x >> 6, l = threadIdx.x & 63;
    const int i = blockIdx.x * 4 + w;

    const int jown = candi[(size_t)i * 32 + (l & 31)] & 8191;

    const int c = l >> 1, h = l & 1;
    const int jc = __shfl(jown, c);
    const float* eprow = &eh[(size_t)i * 256 + h * 128];
    const float* etrow = &et[(size_t)jc * 256 + h * 128];
    double acc = 0.0, acc2 = 0.0;
    #pragma unroll 4
    for (int q = 0; q < 32; q += 2) {
        f32x4 a0 = *(const f32x4*)&eprow[q * 4];
        f32x4 b0 = *(const f32x4*)&etrow[q * 4];
        f32x4 a1 = *(const f32x4*)&eprow[q * 4 + 4];
        f32x4 b1 = *(const f32x4*)&etrow[q * 4 + 4];
        acc  += (double)a0[0] * b0[0] + (double)a0[1] * b0[1] +
                (double)a0[2] * b0[2] + (double)a0[3] * b0[3];
        acc2 += (double)a1[0] * b1[0] + (double)a1[1] * b1[1] +
                (double)a1[2] * b1[2] + (double)a1[3] * b1[3];
    }
    double p = acc + acc2;
    p += __shfl_xor(p, 1);
    p *= 0.0625;

    double v = __shfl(p, 2 * (l & 31));

    float wf[6]; int selj[6];
    #pragma unroll
    for (int s = 0; s < 6; s++) {
        double bv = v; int bj = jown;
        #pragma unroll
        for (int st = 1; st < 64; st <<= 1) {
            double ov = __shfl_xor(bv, st);
            int oj = __shfl_xor(bj, st);
            bool take = (ov > bv) || (ov == bv && oj < bj);
            bv = take ? ov : bv;
            bj = take ? oj : bj;
        }
        wf[s] = (float)bv; selj[s] = bj;
        if (jown == bj) v = -1.0e300;
    }

    float sp[6];
    {
        float mx = wf[0];
        #pragma unroll
        for (int s = 1; s < 6; s++) mx = fmaxf(mx, wf[s]);
        float se = 0.0f, e6[6];
        #pragma unroll
        for (int s = 0; s < 6; s++) { e6[s] = expf(wf[s] - mx); se += e6[s]; }
        #pragma unroll
        for (int s = 0; s < 6; s++) sp[s] = e6[s] / se;
    }

    f32x4 eh4 = *(const f32x4*)&eh[(size_t)i * 256 + l * 4];
    f32x4 nb[6];
    #pragma unroll
    for (int k = 0; k < 6; k++)
        nb[k] = *(const f32x4*)&et[(size_t)selj[k] * 256 + l * 4];

    float pgs[6], pns[6];
    #pragma unroll
    for (int k = 0; k < 6; k++) {
        const float pk = sp[k];
        float pg = 0.0f;
        #pragma unroll
        for (int e = 0; e < 4; e++) {
            float ehd = eh4[e], nbd = nb[k][e];
            float ehr = pk * nbd + (1.0f - pk) * ehd;
            pg += tanhf(ehd + ehr);
        }
        #pragma unroll
        for (int st = 1; st < 64; st <<= 1) pg += __shfl_xor(pg, st);
        pgs[k] = pg;
        pns[k] = rowsum[selj[k]];
    }

    float skp[6];
    {
        float ka[6], mx = -3.0e38f, se = 0.0f;
        #pragma unroll
        for (int k = 0; k < 6; k++) { ka[k] = pns[k] * pgs[k]; mx = fmaxf(mx, ka[k]); }
        #pragma unroll
        for (int k = 0; k < 6; k++) { ka[k] = expf(ka[k] - mx); se += ka[k]; }
        #pragma unroll
        for (int k = 0; k < 6; k++) skp[k] = ka[k] / se;
    }

    f32x4 enh = {0.0f, 0.0f, 0.0f, 0.0f};
    #pragma unroll
    for (int k = 0; k < 6; k++) {
        const float kp = skp[k];
        #pragma unroll
        for (int e = 0; e < 4; e++) enh[e] += kp * nb[k][e];
    }
    short4v h1, h2;
    #pragma unroll
    for (int e = 0; e < 4; e++) {
        h1[e] = (short)f2bf(eh4[e] + enh[e]);
        h2[e] = (short)f2bf(eh4[e] * enh[e]);
    }
    *(short4v*)&m1[(size_t)i * 256 + l * 4] = h1;
    *(short4v*)&m2[(size_t)i * 256 + l * 4] = h2;
}

// ---------------------------------------------------------------------------
__launch_bounds__(256)
__global__ void gate2_k(const float* __restrict__ g1, const float* __restrict__ Ag2,
                        const float* __restrict__ bg2, float* __restrict__ glog) {
    const int i = blockIdx.x * 256 + threadIdx.x;
    float s = 0.0f;
    #pragma unroll 4
    for (int h = 0; h < 128; h++) s += g1[(size_t)i * 128 + h] * Ag2[h];
    glog[i] = s + bg2[0];
}

__launch_bounds__(1024)
__global__ void softmax_g(const float* __restrict__ glog, float* __restrict__ gexp,
                          float* __restrict__ scal) {
    const int t = threadIdx.x;
    __shared__ float red[1024];
    float v[8];
    float m = -3.0e38f;
    #pragma unroll
    for (int c = 0; c < 8; c++) { v[c] = glog[t + c * 1024]; m = fmaxf(m, v[c]); }
    red[t] = m; __syncthreads();
    for (int st = 512; st > 0; st >>= 1) {
        if (t < st) red[t] = fmaxf(red[t], red[t + st]);
        __syncthreads();
    }
    float gm = red[0]; __syncthreads();
    float s = 0.0f;
    #pragma unroll
    for (int c = 0; c < 8; c++) {
        float e = expf(v[c] - gm);
        gexp[t + c * 1024] = e;
        s += e;
    }
    red[t] = s; __syncthreads();
    for (int st = 512; st > 0; st >>= 1) {
        if (t < st) red[t] += red[t + st];
        __syncthreads();
    }
    if (t == 0) scal[0] = 1.0f / red[0];
}

__launch_bounds__(256)
__global__ void wsum_k(const float* __restrict__ emsg, const float* __restrict__ gexp,
                       float* __restrict__ egp) {
    const int b = blockIdx.x, d = threadIdx.x;
    float s = 0.0f;
    const int i0 = b * 128;
    for (int i = 0; i < 128; i++) s += gexp[i0 + i] * emsg[(size_t)(i0 + i) * 256 + d];
    egp[b * 256 + d] = s;
}
__global__ void egfinal_f(const float* __restrict__ egp, const float* __restrict__ scal,
                          float* __restrict__ out) {
    const int d = threadIdx.x;
    float s = 0.0f;
    for (int b = 0; b < 64; b++) s += egp[b * 256 + d];
    out[d] = s * scal[0];
}

__global__ void wsbad_k(float* __restrict__ out) { out[3] = 9000.0f; }

// ---------------------------------------------------------------------------
extern "C" void kernel_launch(void* const* d_in, const int* in_sizes, int n_in,
                              void* d_out, int out_size, void* d_ws, size_t ws_size,
                              hipStream_t stream) {
    (void)in_sizes; (void)n_in; (void)out_size;
    const float* x_path = (const float*)d_in[0];
    const float* fc1_W  = (const float*)d_in[1];
    const float* fc1_b  = (const float*)d_in[2];
    const float* Wh     = (const float*)d_in[3];
    const float* bh     = (const float*)d_in[4];
    const float* Wt     = (const float*)d_in[5];
    const float* bt     = (const float*)d_in[6];
    const float* W1     = (const float*)d_in[7];
    const float* b1     = (const float*)d_in[8];
    const float* W2     = (const float*)d_in[9];
    const float* b2     = (const float*)d_in[10];
    const float* Ag1    = (const float*)d_in[11];
    const float* bg1    = (const float*)d_in[12];
    const float* Ag2    = (const float*)d_in[13];
    const float* bg2    = (const float*)d_in[14];
    float* out_f = (float*)d_out;   // fp32: e_msg [0,2097152), e_g [2097152,2097408)

    const size_t WS_NEEDED = 26412048;
    if (ws_size < WS_NEEDED) {
        hipLaunchKernelGGL(wsbad_k, dim3(1), dim3(1), 0, stream, out_f);
        return;
    }

    char* ws = (char*)d_ws;
    float* x     = (float*)(ws + 0);
    unsigned short* eh16 = (unsigned short*)(ws + 0);
    unsigned short* et16 = (unsigned short*)(ws + 4194304);
    unsigned short* m1b  = (unsigned short*)(ws + 0);
    unsigned short* m2b  = (unsigned short*)(ws + 4194304);
    float* g1    = (float*)(ws + 0);          // 8192x128 fp32 (after m1b/m2b dead)
    float* eh    = (float*)(ws + 8388608);
    float* emsg  = out_f;                     // e_msg written straight to d_out
    float* et    = (float*)(ws + 16777216);
    int*   candi = (int*)  (ws + 25165824);
    float* rowsum= (float*)(ws + 26214400);   // meanp slot (dead after meanred)
    float* meanp = (float*)(ws + 26214400);
    float* meanv = (float*)(ws + 26279936);
    float* glog  = (float*)(ws + 26280960);
    float* gexp  = (float*)(ws + 26313728);
    float* egp   = (float*)(ws + 26346496);
    float* scal  = (float*)(ws + 26412032);

    // weight planes in temporarily-dead regions (all stream-ordered safe):
    unsigned short* Fp = (unsigned short*)(ws + 16777216);   // fc1, in et region
    unsigned short* WHp = (unsigned short*)(ws + 25165824);  // in candi region
    unsigned short* WTp = (unsigned short*)(ws + 25559040);
    unsigned short* P1 = (unsigned short*)(ws + 16777216);   // in et region (post-stageD)
    unsigned short* P2 = (unsigned short*)(ws + 17170432);
    unsigned short* Gp = (unsigned short*)(ws + 25165824);   // in candi region (post-stageD)

    dim3 gg(4, 128);
    // 1) x = leaky(x_path @ fc1_W + fc1_b)  [MFMA 3-split]
    hipLaunchKernelGGL(tsplit3, dim3(8, 32), dim3(256), 0, stream,
                       fc1_W, Fp, 1024, 256, 262144);
    hipLaunchKernelGGL((gemmM<1, 1, 0>), gg, dim3(256), 0, stream,
                       (const void*)x_path, Fp, fc1_b, x, 256, 1024, 262144);
    // 2) x = (x + mean(x)) * 0.5
    hipLaunchKernelGGL(colsum_k, dim3(64), dim3(256), 0, stream, x, meanp);
    hipLaunchKernelGGL(meanred_k, dim3(1), dim3(256), 0, stream, meanp, meanv);
    hipLaunchKernelGGL(finalize_x, dim3(2048), dim3(256), 0, stream, x, meanv);
    // 3) e_h, e_t  [MFMA 3-split, fp32-accurate]
    hipLaunchKernelGGL(tsplit3, dim3(8, 8), dim3(256), 0, stream,
                       Wh, WHp, 256, 256, 65536);
    hipLaunchKernelGGL(tsplit3, dim3(8, 8), dim3(256), 0, stream,
                       Wt, WTp, 256, 256, 65536);
    hipLaunchKernelGGL((gemmM<1, 0, 0>), gg, dim3(256), 0, stream,
                       (const void*)x, WHp, bh, eh, 256, 256, 65536);
    hipLaunchKernelGGL((gemmM<1, 0, 0>), gg, dim3(256), 0, stream,
                       (const void*)x, WTp, bt, et, 256, 256, 65536);
    // 4) bf16 copies for screening + et row sums
    hipLaunchKernelGGL(f2bf_k, dim3(2048), dim3(256), 0, stream, eh, eh16, 524288);
    hipLaunchKernelGGL(f2bf_k, dim3(2048), dim3(256), 0, stream, et, et16, 524288);
    hipLaunchKernelGGL(rowsum_k, dim3(2048), dim3(256), 0, stream, et, rowsum);
    // 5) screening: 512-thr blocks, 128 rows, 2-tile groups, 1 block/CU
    hipLaunchKernelGGL(screen2, dim3(4, 64), dim3(512), 0, stream, eh16, et16, candi);
    // 6) fp64 select + message -> m1b/m2b
    hipLaunchKernelGGL(stageD, dim3(2048), dim3(256), 0, stream, eh, et, rowsum,
                       candi, m1b, m2b);
    // 7) e_msg = leaky(m1@W1+b1) + leaky(m2@W2+b2)  -> straight into out_f
    hipLaunchKernelGGL(tsplit3, dim3(8, 8), dim3(256), 0, stream,
                       W1, P1, 256, 256, 65536);
    hipLaunchKernelGGL(tsplit3, dim3(8, 8), dim3(256), 0, stream,
                       W2, P2, 256, 256, 65536);
    hipLaunchKernelGGL((gemmM<0, 1, 0>), gg, dim3(256), 0, stream,
                       (const void*)m1b, P1, b1, emsg, 256, 256, 65536);
    hipLaunchKernelGGL((gemmM<0, 1, 1>), gg, dim3(256), 0, stream,
                       (const void*)m2b, P2, b2, emsg, 256, 256, 65536);
    // 8) readout: g1 = leaky(emsg@Ag1+bg1) [MFMA 3-split]; then small ops
    hipLaunchKernelGGL(tsplit3, dim3(4, 8), dim3(256), 0, stream,
                       Ag1, Gp, 256, 128, 32768);
    hipLaunchKernelGGL((gemmM<1, 1, 0>), dim3(2, 128), dim3(256), 0, stream,
                       (const void*)emsg, Gp, bg1, g1, 128, 256, 32768);
    hipLaunchKernelGGL(gate2_k, dim3(32), dim3(256), 0, stream, g1, Ag2, bg2, glog);
    hipLaunchKernelGGL(softmax_g, dim3(1), dim3(1024), 0, stream, glog, gexp, scal);
    hipLaunchKernelGGL(wsum_k, dim3(64), dim3(256), 0, stream, emsg, gexp, egp);
    hipLaunchKernelGGL(egfinal_f, dim3(1), dim3(256), 0, stream, egp, scal, out_f + 2097152);
}

// Round 9
// 336.354 us; speedup vs baseline: 1.1238x; 1.0788x over previous
//
#include <hip/hip_runtime.h>

// MOTCAT_Surv R19. R18 passed (absmax 0.0156, 362.9 us); stageD top again (64.7 us,
// VALU 40%, HBM 3.8%) -- phase-1 gather is TRANSACTION-bound: lane-pair half-row
// split puts 64 scattered 16B accesses in each wave load instr (~4096 trans/wave,
// 8x the 512 floor). R19 stageD: (a) 8 lanes/candidate x 4 passes -> each load
// instr = 8 rows x 128B contiguous (16 trans, 4x cut); eh reads become broadcasts;
// fp64 op count unchanged (sum order delta ~1e-15, same class as R13). (b) packed-
// key argmax: slot c in fp64 mantissa low-5 bits; 6 rounds x 5-step fmax butterfly
// (single 64b op/step) replaces 36-step (v,j)-pair chain; kill by exact key
// equality; tie-break differs only at 2^-47-rel score agreement. (c) selj via 6
// wave-uniform shuffles. Plus: f2bf x2 + rowsum fused into one prep_k (3 launches
// -> 1, et read once). Everything else byte-identical to R18 (proven).

typedef __attribute__((ext_vector_type(8))) short short8;
typedef __attribute__((ext_vector_type(4))) short short4v;
typedef __attribute__((ext_vector_type(4))) float f32x4;

__device__ inline float bf2f(unsigned short b) {
    unsigned u = ((unsigned)b) << 16;
    return __builtin_bit_cast(float, u);
}
__device__ inline unsigned short f2bf(float f) {   // round-to-nearest-even
    unsigned u = __builtin_bit_cast(unsigned, f);
    unsigned r = u + 0x7fffu + ((u >> 16) & 1u);
    return (unsigned short)(r >> 16);
}
__device__ inline f32x4 mfma16(short8 a, short8 b, f32x4 c) {
    return __builtin_amdgcn_mfma_f32_16x16x32_bf16(a, b, c, 0, 0, 0);
}
// A-frag: lane holds A[m=lane&15][k=(lane>>4)*8+j]; B-frag: B[k][n=lane&15];
// C/D: col=lane&15 (n), row=(lane>>4)*4+reg (m) (learn_hip m89).

__device__ inline void gload_lds16(const unsigned short* g, unsigned short* l) {
    __builtin_amdgcn_global_load_lds(
        (const __attribute__((address_space(1))) void*)g,
        (__attribute__((address_space(3))) void*)l, 16, 0, 0);
}

// split fp32 -> bf16 hi/mid/lo (residual subtractions are exact: operands close)
__device__ inline void split8(const f32x4 v0, const f32x4 v1,
                              short8& hi, short8& md, short8& lo) {
    #pragma unroll
    for (int e = 0; e < 8; e++) {
        float a = (e < 4) ? v0[e] : v1[e - 4];
        unsigned short h = f2bf(a);
        float r1 = a - bf2f(h);
        unsigned short m = f2bf(r1);
        float r2 = r1 - bf2f(m);
        unsigned short l = f2bf(r2);
        hi[e] = (short)h; md[e] = (short)m; lo[e] = (short)l;
    }
}

// ---------------------------------------------------------------------------
// tsplit3: W [K][N] fp32 -> Bt planes [n][k] bf16 (hi, mid, lo) at out + p*PS.
// ---------------------------------------------------------------------------
__launch_bounds__(256)
__global__ void tsplit3(const float* __restrict__ W, unsigned short* __restrict__ out,
                        int K, int N, int PS) {
    __shared__ float T[32][33];
    const int t = threadIdx.x;
    const int n0 = blockIdx.x * 32, k0 = blockIdx.y * 32;
    {
        const int r = t >> 3, c = (t & 7) * 4;
        f32x4 v = *(const f32x4*)&W[(size_t)(k0 + r) * N + n0 + c];
        #pragma unroll
        for (int e = 0; e < 4; e++) T[r][c + e] = v[e];
    }
    __syncthreads();
    const int nr = t >> 3, kc = (t & 7) * 4;
    short4v h4, m4, l4;
    #pragma unroll
    for (int e = 0; e < 4; e++) {
        float a = T[kc + e][nr];
        unsigned short h = f2bf(a);
        float r1 = a - bf2f(h);
        unsigned short m = f2bf(r1);
        float r2 = r1 - bf2f(m);
        h4[e] = (short)h; m4[e] = (short)m; l4[e] = (short)f2bf(r2);
    }
    const size_t o = (size_t)(n0 + nr) * K + k0 + kc;
    *(short4v*)&out[o] = h4;
    *(short4v*)&out[(size_t)PS + o] = m4;
    *(short4v*)&out[(size_t)2 * PS + o] = l4;
}

// ---------------------------------------------------------------------------
// gemmM (proven R15): C = act(A@B + bias) (+=C if ACCUM) on matrix cores.
// ---------------------------------------------------------------------------
template <int ASPLIT, int ACT, int ACCUM>
__launch_bounds__(256)
__global__ void gemmM(const void* __restrict__ Av,
                      const unsigned short* __restrict__ Bt,
                      const float* __restrict__ bias, float* __restrict__ C,
                      int N, int K, int BPS) {
    constexpr int APL = ASPLIT ? 3 : 1;
    constexpr int BPL = ASPLIT ? 3 : 2;
    __shared__ __align__(16) unsigned short LA[2][APL * 2048];
    __shared__ __align__(16) unsigned short LB[2][BPL * 2048];
    const int t = threadIdx.x;
    const int r0 = blockIdx.y * 64, c0 = blockIdx.x * 64;
    const int lid = t & 63, w = t >> 6, g = lid >> 4, m16 = lid & 15;
    const int wm = w >> 1, wn = w & 1;

    f32x4 acc[2][2];
    #pragma unroll
    for (int mf = 0; mf < 2; mf++)
        #pragma unroll
        for (int nf = 0; nf < 2; nf++) acc[mf][nf] = {0.0f, 0.0f, 0.0f, 0.0f};

    const int KT = K >> 5;
    const size_t aoff = (size_t)(r0 + (t >> 2)) * K + (t & 3) * 8;
    const size_t boff = (size_t)(c0 + (t >> 2)) * K + (t & 3) * 8;

    {
        #pragma unroll
        for (int p = 0; p < BPL; p++)
            gload_lds16(&Bt[(size_t)p * BPS + boff], &LB[0][p * 2048 + 8 * t]);
        if (ASPLIT) {
            const float* A = (const float*)Av;
            f32x4 v0 = *(const f32x4*)&A[aoff];
            f32x4 v1 = *(const f32x4*)&A[aoff + 4];
            short8 hi, md, lo;
            split8(v0, v1, hi, md, lo);
            *(short8*)&LA[0][8 * t] = hi;
            *(short8*)&LA[0][2048 + 8 * t] = md;
            *(short8*)&LA[0][4096 + 8 * t] = lo;
        } else {
            const unsigned short* A16 = (const unsigned short*)Av;
            gload_lds16(&A16[aoff], &LA[0][8 * t]);
        }
    }
    __syncthreads();

    for (int kt = 0; kt < KT; kt++) {
        const int cur = kt & 1, nxt = cur ^ 1;
        const bool hn = (kt + 1) < KT;
        f32x4 v0, v1;
        if (hn) {
            const size_t ko = (size_t)(kt + 1) * 32;
            #pragma unroll
            for (int p = 0; p < BPL; p++)
                gload_lds16(&Bt[(size_t)p * BPS + boff + ko],
                            &LB[nxt][p * 2048 + 8 * t]);
            if (ASPLIT) {
                const float* A = (const float*)Av;
                v0 = *(const f32x4*)&A[aoff + ko];
                v1 = *(const f32x4*)&A[aoff + ko + 4];
            } else {
                const unsigned short* A16 = (const unsigned short*)Av;
                gload_lds16(&A16[aoff + ko], &LA[nxt][8 * t]);
            }
        }
        short8 af[2][APL], bf[2][BPL];
        #pragma unroll
        for (int mf = 0; mf < 2; mf++) {
            const int row = wm * 32 + mf * 16 + m16;
            #pragma unroll
            for (int p = 0; p < APL; p++)
                af[mf][p] = *(const short8*)&LA[cur][p * 2048 + row * 32 + g * 8];
        }
        #pragma unroll
        for (int nf = 0; nf < 2; nf++) {
            const int col = wn * 32 + nf * 16 + m16;
            #pragma unroll
            for (int p = 0; p < BPL; p++)
                bf[nf][p] = *(const short8*)&LB[cur][p * 2048 + col * 32 + g * 8];
        }
        #pragma unroll
        for (int mf = 0; mf < 2; mf++)
            #pragma unroll
            for (int nf = 0; nf < 2; nf++) {
                if (ASPLIT) {
                    acc[mf][nf] = mfma16(af[mf][0], bf[nf][0], acc[mf][nf]); // hh
                    acc[mf][nf] = mfma16(af[mf][0], bf[nf][1], acc[mf][nf]); // hm
                    acc[mf][nf] = mfma16(af[mf][1], bf[nf][0], acc[mf][nf]); // mh
                    acc[mf][nf] = mfma16(af[mf][0], bf[nf][2], acc[mf][nf]); // hl
                    acc[mf][nf] = mfma16(af[mf][1], bf[nf][1], acc[mf][nf]); // mm
                    acc[mf][nf] = mfma16(af[mf][2], bf[nf][0], acc[mf][nf]); // lh
                } else {
                    acc[mf][nf] = mfma16(af[mf][0], bf[nf][0], acc[mf][nf]);
                    acc[mf][nf] = mfma16(af[mf][0], bf[nf][1], acc[mf][nf]);
                }
            }
        if (hn && ASPLIT) {
            short8 hi, md, lo;
            split8(v0, v1, hi, md, lo);
            *(short8*)&LA[nxt][8 * t] = hi;
            *(short8*)&LA[nxt][2048 + 8 * t] = md;
            *(short8*)&LA[nxt][4096 + 8 * t] = lo;
        }
        __syncthreads();
    }

    #pragma unroll
    for (int nf = 0; nf < 2; nf++) {
        const int col = c0 + wn * 32 + nf * 16 + m16;
        const float bv = bias[col];
        #pragma unroll
        for (int mf = 0; mf < 2; mf++) {
            #pragma unroll
            for (int r = 0; r < 4; r++) {
                const int row = r0 + wm * 32 + mf * 16 + g * 4 + r;
                float v = acc[mf][nf][r] + bv;
                if (ACT == 1) v = v > 0.0f ? v : 0.01f * v;
                size_t idx = (size_t)row * N + col;
                if (ACCUM) v += C[idx];
                C[idx] = v;
            }
        }
    }
}

// ---------------------------------------------------------------------------
__global__ void colsum_k(const float* __restrict__ x, float* __restrict__ out) {
    int d = threadIdx.x, b = blockIdx.x;
    float s = 0.0f;
    int i0 = b * 128;
    for (int i = 0; i < 128; i++) s += x[(size_t)(i0 + i) * 256 + d];
    out[b * 256 + d] = s;
}
__global__ void meanred_k(const float* __restrict__ p, float* __restrict__ mean) {
    int d = threadIdx.x;
    float s = 0.0f;
    for (int b = 0; b < 64; b++) s += p[b * 256 + d];
    mean[d] = s * (1.0f / 8192.0f);
}
__global__ void finalize_x(float* __restrict__ x, const float* __restrict__ mean) {
    size_t idx = (size_t)blockIdx.x * blockDim.x + threadIdx.x;
    f32x4 v = *(f32x4*)&x[idx * 4];
    int d4 = (int)((idx * 4) & 255);
    f32x4 m = *(const f32x4*)&mean[d4];
    #pragma unroll
    for (int e = 0; e < 4; e++) v[e] = (v[e] + m[e]) * 0.5f;
    *(f32x4*)&x[idx * 4] = v;
}
// prep_k: blocks 0..2047: eh -> eh16 (f2bf); blocks 2048..4095: et -> et16 + rowsum.
__launch_bounds__(256)
__global__ void prep_k(const float* __restrict__ eh, const float* __restrict__ et,
                       unsigned short* __restrict__ eh16,
                       unsigned short* __restrict__ et16,
                       float* __restrict__ rowsum) {
    const int b = blockIdx.x;
    if (b < 2048) {
        size_t idx = (size_t)b * 256 + threadIdx.x;
        f32x4 v = *(const f32x4*)&eh[idx * 4];
        short4v h;
        #pragma unroll
        for (int e = 0; e < 4; e++) h[e] = (short)f2bf(v[e]);
        *(short4v*)&eh16[idx * 4] = h;
    } else {
        const int w = threadIdx.x >> 6, l = threadIdx.x & 63;
        const int i = (b - 2048) * 4 + w;
        f32x4 v = *(const f32x4*)&et[(size_t)i * 256 + l * 4];
        short4v h;
        #pragma unroll
        for (int e = 0; e < 4; e++) h[e] = (short)f2bf(v[e]);
        *(short4v*)&et16[(size_t)i * 256 + l * 4] = h;
        float s = v[0] + v[1] + v[2] + v[3];
        #pragma unroll
        for (int st = 1; st < 64; st <<= 1) s += __shfl_xor(s, st);
        if (l == 0) rowsum[i] = s;
    }
}

// ---------------------------------------------------------------------------
// float keys (col in low-11 mantissa bits), med3 insert. Ascending, tk[0]=min.
// ---------------------------------------------------------------------------
__device__ inline float packkey(float v, unsigned col) {
    unsigned u = (__builtin_bit_cast(unsigned, v) & 0xFFFFF800u) | col;
    return __builtin_bit_cast(float, u);
}
template<int NK>
__device__ inline void insf(float (&tk)[NK], float key) {
    #pragma unroll
    for (int k = 0; k < NK - 1; k++)
        tk[k] = __builtin_amdgcn_fmed3f(key, tk[k + 1], tk[k]);
    tk[NK - 1] = fmaxf(tk[NK - 1], key);
}

// ---------------------------------------------------------------------------
// screen2 (proven R18): 512 thr = 8 waves, 128 rows/block, grid (4,64), 2-tile
// groups double-buffered, 1 barrier per group. Wave = rowset x col-half.
// ---------------------------------------------------------------------------
__launch_bounds__(512)
__global__ void screen2(const unsigned short* __restrict__ eh16,
                        const unsigned short* __restrict__ et16,
                        int* __restrict__ candi) {
    __shared__ __align__(16) unsigned short Bs[2][2][8192];  // [buf][tile-in-group]
    __shared__ float mbuf[8][2][16][8];                      // [rowgrp][half][m16][q]
    const int t = threadIdx.x;
    const int cs = blockIdx.x;
    const int r0 = blockIdx.y * 128;
    const int w = t >> 6, lid = t & 63, lg = lid >> 4, m16 = lid & 15;
    const int rs = w >> 1, ch = w & 1;

    short8 bfr[2][8];   // eh B-frags: rows r0+rs*32+s*16+m16, k = ks*32 + lg*8 + j
    #pragma unroll
    for (int s = 0; s < 2; s++)
        #pragma unroll
        for (int ks = 0; ks < 8; ks++)
            bfr[s][ks] = *(const short8*)
                &eh16[(size_t)(r0 + rs * 32 + s * 16 + m16) * 256 + ks * 32 + lg * 8];

    float tk0[6], tk1[6];
    #pragma unroll
    for (int q = 0; q < 6; q++) { tk0[q] = -3.0e38f; tk1[q] = -3.0e38f; }

    int scol[2], goff[2], ldsl[2];
    #pragma unroll
    for (int c = 0; c < 2; c++) {
        int L = (w * 2 + c) * 64 + lid;
        int col = L >> 5, gs = L & 31;
        int gorig = (gs & 24) | ((gs ^ col) & 7);
        scol[c] = col; goff[c] = gorig * 8; ldsl[c] = L * 8;
    }

    #pragma unroll
    for (int tt = 0; tt < 2; tt++) {
        const int j0 = cs * 2048 + tt * 32;
        #pragma unroll
        for (int c = 0; c < 2; c++)
            gload_lds16(&et16[(size_t)(j0 + scol[c]) * 256 + goff[c]],
                        &Bs[0][tt][ldsl[c]]);
    }
    __syncthreads();

    const int swz = m16 & 7;
    const int cbase = (ch * 16 + m16) * 32;
    for (int gi = 0; gi < 32; gi++) {
        const int cur = gi & 1;
        if (gi + 1 < 32) {
            #pragma unroll
            for (int tt = 0; tt < 2; tt++) {
                const int j1 = cs * 2048 + ((gi + 1) * 2 + tt) * 32;
                #pragma unroll
                for (int c = 0; c < 2; c++)
                    gload_lds16(&et16[(size_t)(j1 + scol[c]) * 256 + goff[c]],
                                &Bs[cur ^ 1][tt][ldsl[c]]);
            }
        }
        #pragma unroll
        for (int tt = 0; tt < 2; tt++) {
            const int tile = gi * 2 + tt;
            const unsigned short* bst = Bs[cur][tt];
            f32x4 a0 = {0.0f, 0.0f, 0.0f, 0.0f}, a1 = a0;
            #pragma unroll
            for (int ks = 0; ks < 8; ks++) {
                const int gq = ks * 4 + lg;
                short8 e = *(const short8*)&bst[(cbase + (gq ^ swz)) * 8];
                a0 = mfma16(e, bfr[0][ks], a0);
                a1 = mfma16(e, bfr[1][ks], a1);
            }
            const unsigned cb = (unsigned)(tile * 32 + ch * 16 + lg * 4);
            #pragma unroll
            for (int r = 0; r < 4; r++) {
                insf<6>(tk0, packkey(a0[r], cb + (unsigned)r));
                insf<6>(tk1, packkey(a1[r], cb + (unsigned)r));
            }
        }
        __syncthreads();
    }

    #pragma unroll
    for (int s = 0; s < 2; s++) {
        float tk8[8];
        tk8[0] = -3.0e38f; tk8[1] = -3.0e38f;
        #pragma unroll
        for (int q = 0; q < 6; q++) tk8[q + 2] = s ? tk1[q] : tk0[q];
        #pragma unroll
        for (int step = 16; step <= 32; step <<= 1) {
            float ok[8];
            #pragma unroll
            for (int q = 0; q < 8; q++) ok[q] = __shfl_xor(tk8[q], step);
            #pragma unroll
            for (int q = 0; q < 8; q++) insf<8>(tk8, ok[q]);
        }
        if (lg == 0) {
            #pragma unroll
            for (int q = 0; q < 8; q++) mbuf[rs * 2 + s][ch][m16][q] = tk8[q];
        }
    }
    __syncthreads();

    if (t < 128) {
        float tk8[8];
        #pragma unroll
        for (int q = 0; q < 8; q++) tk8[q] = mbuf[t >> 4][0][t & 15][q];
        #pragma unroll
        for (int q = 0; q < 8; q++) insf<8>(tk8, mbuf[t >> 4][1][t & 15][q]);
        const int row = r0 + t;
        #pragma unroll
        for (int q = 0; q < 8; q++)
            candi[(size_t)row * 32 + cs * 8 + q] =
                cs * 2048 + (int)(__builtin_bit_cast(unsigned, tk8[q]) & 0x7FFu);
    }
}

// ---------------------------------------------------------------------------
// Stage D R19: LDS-free, barrier-free; 4 waves/block, one row per wave.
// Phase 1: 4 passes, 8 lanes/candidate -> each wave load instr = 8 rows x 128B
// contiguous (coalesced); 3-step group reduce; redistribute via 4 shuffles.
// Phase 2: packed fp64 keys (slot c in mantissa low-5 bits); 6 rounds of 5-step
// fmax butterfly; kill by exact key equality; selj via wave-uniform shuffles.
// Phase 3: unchanged (per-lane d-slice message, butterfly pg sums).
// ---------------------------------------------------------------------------
__launch_bounds__(256)
__global__ void stageD(const float* __restrict__ eh, const float* __restrict__ et,
                       const float* __restrict__ rowsum,
                       const int* __restrict__ candi,
                       unsigned short* __restrict__ m1, unsigned short* __restrict__ m2) {
    const int w = threadIdx.x >> 6, l = threadIdx.x & 63;
    const int i = blockIdx.x * 4 + w;
    const int c_own = l & 31;

    const int jown = candi[(size_t)i * 32 + c_own] & 8191;

    // ---- phase 1: fp64 rescore, 8 lanes per candidate, 4 passes ----
    const int q = l & 7, g8 = l >> 3;
    const float* er = &eh[(size_t)i * 256];
    double vres[4];
    #pragma unroll
    for (int p = 0; p < 4; p++) {
        const int cc = p * 8 + g8;
        const int jc = __shfl(jown, cc);
        const float* tr = &et[(size_t)jc * 256];
        double a = 0.0;
        #pragma unroll
        for (int tt = 0; tt < 8; tt++) {
            const int o = (tt * 8 + q) * 4;
            f32x4 av = *(const f32x4*)&er[o];
            f32x4 bv = *(const f32x4*)&tr[o];
            a += (double)av[0] * bv[0] + (double)av[1] * bv[1] +
                 (double)av[2] * bv[2] + (double)av[3] * bv[3];
        }
        a += __shfl_xor(a, 1);
        a += __shfl_xor(a, 2);
        a += __shfl_xor(a, 4);
        vres[p] = a * 0.0625;
    }
    // redistribute: lane l needs candidate c_own's score (computed in pass
    // c_own>>3 by lane group (c_own&7))
    const int src = (c_own & 7) * 8;
    double t0 = __shfl(vres[0], src), t1 = __shfl(vres[1], src);
    double t2 = __shfl(vres[2], src), t3 = __shfl(vres[3], src);
    const int ps = c_own >> 3;
    double v = ps == 0 ? t0 : ps == 1 ? t1 : ps == 2 ? t2 : t3;

    // ---- phase 2: packed-key top-6 (5-step fmax butterflies) ----
    unsigned long long kb = __builtin_bit_cast(unsigned long long, v);
    double key = __builtin_bit_cast(double, (kb & ~31ULL) | (unsigned long long)c_own);
    float wf[6]; int selc[6];
    #pragma unroll
    for (int s = 0; s < 6; s++) {
        double b = key;
        #pragma unroll
        for (int st = 1; st < 32; st <<= 1) {
            double ob = __shfl_xor(b, st);
            b = b > ob ? b : ob;
        }
        selc[s] = (int)(__builtin_bit_cast(unsigned long long, b) & 31ULL);
        wf[s] = (float)b;
        if (key == b) key = -1.0e300;   // kill winner (keys unique)
    }
    int selj[6];
    #pragma unroll
    for (int s = 0; s < 6; s++) selj[s] = __shfl(jown, selc[s]);

    // softmax over the 6 selected logits (redundant per-lane)
    float sp[6];
    {
        float mx = wf[0];
        #pragma unroll
        for (int s = 1; s < 6; s++) mx = fmaxf(mx, wf[s]);
        float se = 0.0f, e6[6];
        #pragma unroll
        for (int s = 0; s < 6; s++) { e6[s] = expf(wf[s] - mx); se += e6[s]; }
        #pragma unroll
        for (int s = 0; s < 6; s++) sp[s] = e6[s] / se;
    }

    // ---- phase 3: message construction, per-lane d-slice ----
    f32x4 eh4 = *(const f32x4*)&eh[(size_t)i * 256 + l * 4];
    f32x4 nb[6];
    #pragma unroll
    for (int k = 0; k < 6; k++)
        nb[k] = *(const f32x4*)&et[(size_t)selj[k] * 256 + l * 4];

    float pgs[6], pns[6];
    #pragma unroll
    for (int k = 0; k < 6; k++) {
        const float pk = sp[k];
        float pg = 0.0f;
        #pragma unroll
        for (int e = 0; e < 4; e++) {
            float ehd = eh4[e], nbd = nb[k][e];
            float ehr = pk * nbd + (1.0f - pk) * ehd;
            pg += tanhf(ehd + ehr);
        }
        #pragma unroll
        for (int st = 1; st < 64; st <<= 1) pg += __shfl_xor(pg, st);
        pgs[k] = pg;
        pns[k] = rowsum[selj[k]];
    }

    float skp[6];
    {
        float ka[6], mx = -3.0e38f, se = 0.0f;
        #pragma unroll
        for (int k = 0; k < 6; k++) { ka[k] = pns[k] * pgs[k]; mx = fmaxf(mx, ka[k]); }
        #pragma unroll
        for (int k = 0; k < 6; k++) { ka[k] = expf(ka[k] - mx); se += ka[k]; }
        #pragma unroll
        for (int k = 0; k < 6; k++) skp[k] = ka[k] / se;
    }

    f32x4 enh = {0.0f, 0.0f, 0.0f, 0.0f};
    #pragma unroll
    for (int k = 0; k < 6; k++) {
        const float kp = skp[k];
        #pragma unroll
        for (int e = 0; e < 4; e++) enh[e] += kp * nb[k][e];
    }
    short4v h1, h2;
    #pragma unroll
    for (int e = 0; e < 4; e++) {
        h1[e] = (short)f2bf(eh4[e] + enh[e]);
        h2[e] = (short)f2bf(eh4[e] * enh[e]);
    }
    *(short4v*)&m1[(size_t)i * 256 + l * 4] = h1;
    *(short4v*)&m2[(size_t)i * 256 + l * 4] = h2;
}

// ---------------------------------------------------------------------------
__launch_bounds__(256)
__global__ void gate2_k(const float* __restrict__ g1, const float* __restrict__ Ag2,
                        const float* __restrict__ bg2, float* __restrict__ glog) {
    const int i = blockIdx.x * 256 + threadIdx.x;
    float s = 0.0f;
    #pragma unroll 4
    for (int h = 0; h < 128; h++) s += g1[(size_t)i * 128 + h] * Ag2[h];
    glog[i] = s + bg2[0];
}

__launch_bounds__(1024)
__global__ void softmax_g(const float* __restrict__ glog, float* __restrict__ gexp,
                          float* __restrict__ scal) {
    const int t = threadIdx.x;
    __shared__ float red[1024];
    float v[8];
    float m = -3.0e38f;
    #pragma unroll
    for (int c = 0; c < 8; c++) { v[c] = glog[t + c * 1024]; m = fmaxf(m, v[c]); }
    red[t] = m; __syncthreads();
    for (int st = 512; st > 0; st >>= 1) {
        if (t < st) red[t] = fmaxf(red[t], red[t + st]);
        __syncthreads();
    }
    float gm = red[0]; __syncthreads();
    float s = 0.0f;
    #pragma unroll
    for (int c = 0; c < 8; c++) {
        float e = expf(v[c] - gm);
        gexp[t + c * 1024] = e;
        s += e;
    }
    red[t] = s; __syncthreads();
    for (int st = 512; st > 0; st >>= 1) {
        if (t < st) red[t] += red[t + st];
        __syncthreads();
    }
    if (t == 0) scal[0] = 1.0f / red[0];
}

__launch_bounds__(256)
__global__ void wsum_k(const float* __restrict__ emsg, const float* __restrict__ gexp,
                       float* __restrict__ egp) {
    const int b = blockIdx.x, d = threadIdx.x;
    float s = 0.0f;
    const int i0 = b * 128;
    for (int i = 0; i < 128; i++) s += gexp[i0 + i] * emsg[(size_t)(i0 + i) * 256 + d];
    egp[b * 256 + d] = s;
}
__global__ void egfinal_f(const float* __restrict__ egp, const float* __restrict__ scal,
                          float* __restrict__ out) {
    const int d = threadIdx.x;
    float s = 0.0f;
    for (int b = 0; b < 64; b++) s += egp[b * 256 + d];
    out[d] = s * scal[0];
}

__global__ void wsbad_k(float* __restrict__ out) { out[3] = 9000.0f; }

// ---------------------------------------------------------------------------
extern "C" void kernel_launch(void* const* d_in, const int* in_sizes, int n_in,
                              void* d_out, int out_size, void* d_ws, size_t ws_size,
                              hipStream_t stream) {
    (void)in_sizes; (void)n_in; (void)out_size;
    const float* x_path = (const float*)d_in[0];
    const float* fc1_W  = (const float*)d_in[1];
    const float* fc1_b  = (const float*)d_in[2];
    const float* Wh     = (const float*)d_in[3];
    const float* bh     = (const float*)d_in[4];
    const float* Wt     = (const float*)d_in[5];
    const float* bt     = (const float*)d_in[6];
    const float* W1     = (const float*)d_in[7];
    const float* b1     = (const float*)d_in[8];
    const float* W2     = (const float*)d_in[9];
    const float* b2     = (const float*)d_in[10];
    const float* Ag1    = (const float*)d_in[11];
    const float* bg1    = (const float*)d_in[12];
    const float* Ag2    = (const float*)d_in[13];
    const float* bg2    = (const float*)d_in[14];
    float* out_f = (float*)d_out;   // fp32: e_msg [0,2097152), e_g [2097152,2097408)

    const size_t WS_NEEDED = 26412048;
    if (ws_size < WS_NEEDED) {
        hipLaunchKernelGGL(wsbad_k, dim3(1), dim3(1), 0, stream, out_f);
        return;
    }

    char* ws = (char*)d_ws;
    float* x     = (float*)(ws + 0);
    unsigned short* eh16 = (unsigned short*)(ws + 0);
    unsigned short* et16 = (unsigned short*)(ws + 4194304);
    unsigned short* m1b  = (unsigned short*)(ws + 0);
    unsigned short* m2b  = (unsigned short*)(ws + 4194304);
    float* g1    = (float*)(ws + 0);          // 8192x128 fp32 (after m1b/m2b dead)
    float* eh    = (float*)(ws + 8388608);
    float* emsg  = out_f;                     // e_msg written straight to d_out
    float* et    = (float*)(ws + 16777216);
    int*   candi = (int*)  (ws + 25165824);
    float* rowsum= (float*)(ws + 26214400);   // meanp slot (dead after meanred)
    float* meanp = (float*)(ws + 26214400);
    float* meanv = (float*)(ws + 26279936);
    float* glog  = (float*)(ws + 26280960);
    float* gexp  = (float*)(ws + 26313728);
    float* egp   = (float*)(ws + 26346496);
    float* scal  = (float*)(ws + 26412032);

    // weight planes in temporarily-dead regions (all stream-ordered safe):
    unsigned short* Fp = (unsigned short*)(ws + 16777216);   // fc1, in et region
    unsigned short* WHp = (unsigned short*)(ws + 25165824);  // in candi region
    unsigned short* WTp = (unsigned short*)(ws + 25559040);
    unsigned short* P1 = (unsigned short*)(ws + 16777216);   // in et region (post-stageD)
    unsigned short* P2 = (unsigned short*)(ws + 17170432);
    unsigned short* Gp = (unsigned short*)(ws + 25165824);   // in candi region (post-stageD)

    dim3 gg(4, 128);
    // 1) x = leaky(x_path @ fc1_W + fc1_b)  [MFMA 3-split]
    hipLaunchKernelGGL(tsplit3, dim3(8, 32), dim3(256), 0, stream,
                       fc1_W, Fp, 1024, 256, 262144);
    hipLaunchKernelGGL((gemmM<1, 1, 0>), gg, dim3(256), 0, stream,
                       (const void*)x_path, Fp, fc1_b, x, 256, 1024, 262144);
    // 2) x = (x + mean(x)) * 0.5
    hipLaunchKernelGGL(colsum_k, dim3(64), dim3(256), 0, stream, x, meanp);
    hipLaunchKernelGGL(meanred_k, dim3(1), dim3(256), 0, stream, meanp, meanv);
    hipLaunchKernelGGL(finalize_x, dim3(2048), dim3(256), 0, stream, x, meanv);
    // 3) e_h, e_t  [MFMA 3-split, fp32-accurate]
    hipLaunchKernelGGL(tsplit3, dim3(8, 8), dim3(256), 0, stream,
                       Wh, WHp, 256, 256, 65536);
    hipLaunchKernelGGL(tsplit3, dim3(8, 8), dim3(256), 0, stream,
                       Wt, WTp, 256, 256, 65536);
    hipLaunchKernelGGL((gemmM<1, 0, 0>), gg, dim3(256), 0, stream,
                       (const void*)x, WHp, bh, eh, 256, 256, 65536);
    hipLaunchKernelGGL((gemmM<1, 0, 0>), gg, dim3(256), 0, stream,
                       (const void*)x, WTp, bt, et, 256, 256, 65536);
    // 4) bf16 copies + et row sums (fused)
    hipLaunchKernelGGL(prep_k, dim3(4096), dim3(256), 0, stream,
                       eh, et, eh16, et16, rowsum);
    // 5) screening: 512-thr blocks, 128 rows, 2-tile groups, 1 block/CU
    hipLaunchKernelGGL(screen2, dim3(4, 64), dim3(512), 0, stream, eh16, et16, candi);
    // 6) fp64 select + message -> m1b/m2b
    hipLaunchKernelGGL(stageD, dim3(2048), dim3(256), 0, stream, eh, et, rowsum,
                       candi, m1b, m2b);
    // 7) e_msg = leaky(m1@W1+b1) + leaky(m2@W2+b2)  -> straight into out_f
    hipLaunchKernelGGL(tsplit3, dim3(8, 8), dim3(256), 0, stream,
                       W1, P1, 256, 256, 65536);
    hipLaunchKernelGGL(tsplit3, dim3(8, 8), dim3(256), 0, stream,
                       W2, P2, 256, 256, 65536);
    hipLaunchKernelGGL((gemmM<0, 1, 0>), gg, dim3(256), 0, stream,
                       (const void*)m1b, P1, b1, emsg, 256, 256, 65536);
    hipLaunchKernelGGL((gemmM<0, 1, 1>), gg, dim3(256), 0, stream,
                       (const void*)m2b, P2, b2, emsg, 256, 256, 65536);
    // 8) readout: g1 = leaky(emsg@Ag1+bg1) [MFMA 3-split]; then small ops
    hipLaunchKernelGGL(tsplit3, dim3(4, 8), dim3(256), 0, stream,
                       Ag1, Gp, 256, 128, 32768);
    hipLaunchKernelGGL((gemmM<1, 1, 0>), dim3(2, 128), dim3(256), 0, stream,
                       (const void*)emsg, Gp, bg1, g1, 128, 256, 32768);
    hipLaunchKernelGGL(gate2_k, dim3(32), dim3(256), 0, stream, g1, Ag2, bg2, glog);
    hipLaunchKernelGGL(softmax_g, dim3(1), dim3(1024), 0, stream, glog, gexp, scal);
    hipLaunchKernelGGL(wsum_k, dim3(64), dim3(256), 0, stream, emsg, gexp, egp);
    hipLaunchKernelGGL(egfinal_f, dim3(1), dim3(256), 0, stream, egp, scal, out_f + 2097152);
}